// Round 5
// baseline (1837.663 us; speedup 1.0000x reference)
//
#include <hip/hip_runtime.h>
#include <cstdio>
#include <cmath>

#define DEV __device__ __forceinline__

static constexpr int NN = 50000;   // nodes
static constexpr int DD = 256;     // input dim
static constexpr int HH = 128;     // hidden
static constexpr int CC = 40;      // classes
static constexpr int KK = 4;       // envs
static constexpr int EE = 800000;  // edges

// harness-named kernel (kept; unused in pipeline)
__global__ void MLEI_12970801234193_kernel(float* out, int n) {
  int i = blockIdx.x * blockDim.x + threadIdx.x;
  if (i < n) out[i] = 7.0f;
}

__global__ void zero_i32_kernel(int* p, int n) {
  int i = blockIdx.x * blockDim.x + threadIdx.x;
  if (i < n) p[i] = 0;
}
__global__ void zero_f32_kernel(float* p, int n) {
  int i = blockIdx.x * blockDim.x + threadIdx.x;
  if (i < n) p[i] = 0.f;
}

// ---------------- unified tiled fp32 GEMM ----------------
// C[M,Nd] = A[M,Kd] * B[Kd,Nd]; 64x64 tile, 256 threads, 4x4 acc/thread.
// amode: 1 plain f32 A (lda) | 2 conv virtual: A[n,k*256+r]=env[n,k]*([agg;h])[n,r]
//        3 ctx virtual: A[n,k*128+r]=genv[n,k]*gr[n,r] | 4 sum: A+A2 (lda=128)
// emode: 0 acc+bias | 1 relu(acc+bias) | 2 relu(acc+resid)
//        3 (resid+acc*red[2])/anorm[m] | 4 plain | 5 0.5*acc+bias (final)
DEV float4 load4A(int amode, const float* A, const float* A2, const float* A3,
                  int lda, int m, int k) {
  if (amode == 1) {
    return *(const float4*)(A + (size_t)m * lda + k);
  } else if (amode == 2) {
    int kk = k >> 8, r = k & 255;
    const float* src = (r < 128) ? (A + (size_t)m * 128 + r)
                                 : (A2 + (size_t)m * 128 + (r - 128));
    float4 v = *(const float4*)src;
    float e = A3[(size_t)m * 4 + kk];
    return make_float4(v.x * e, v.y * e, v.z * e, v.w * e);
  } else if (amode == 3) {
    int kk = k >> 7, r = k & 127;
    float4 v = *(const float4*)(A + (size_t)m * 128 + r);
    float e = A3[(size_t)m * 4 + kk];
    return make_float4(v.x * e, v.y * e, v.z * e, v.w * e);
  } else {
    float4 a = *(const float4*)(A + (size_t)m * 128 + k);
    float4 b = *(const float4*)(A2 + (size_t)m * 128 + k);
    return make_float4(a.x + b.x, a.y + b.y, a.z + b.z, a.w + b.w);
  }
}

DEV float4 load4B(const float* B, int ldb, int k, int n, int Nd) {
  const float* p = B + (size_t)k * ldb;
  if (n + 3 < Nd) return *(const float4*)(p + n);
  float4 r = make_float4(0.f, 0.f, 0.f, 0.f);
  if (n + 0 < Nd) r.x = p[n + 0];
  if (n + 1 < Nd) r.y = p[n + 1];
  if (n + 2 < Nd) r.z = p[n + 2];
  if (n + 3 < Nd) r.w = p[n + 3];
  return r;
}

__global__ __launch_bounds__(256) void gemm_kernel(
    int amode, const float* A, const float* A2, const float* A3, int lda,
    const float* B, int ldb,
    int emode, float* outF, int ldo,
    const float* bias, const float* resid,
    const float* anorm, const float* red,
    int M, int Nd, int Kd) {
  __shared__ __align__(16) float As[16][68];
  __shared__ __align__(16) float Bs[16][68];
  const int tid = threadIdx.x;
  const int bm = blockIdx.x * 64, bn = blockIdx.y * 64;
  const int ty = tid >> 4, tx = tid & 15;
  const int am = tid >> 2, ak = (tid & 3) * 4;
  const int bk = tid >> 4, bnc = (tid & 15) * 4;
  float acc[4][4];
#pragma unroll
  for (int i = 0; i < 4; ++i)
#pragma unroll
    for (int j = 0; j < 4; ++j) acc[i][j] = 0.f;

  for (int k0 = 0; k0 < Kd; k0 += 16) {
    float4 av = (bm + am < M) ? load4A(amode, A, A2, A3, lda, bm + am, k0 + ak)
                              : make_float4(0.f, 0.f, 0.f, 0.f);
    float4 bv = load4B(B, ldb, k0 + bk, bn + bnc, Nd);
    As[ak + 0][am] = av.x; As[ak + 1][am] = av.y;
    As[ak + 2][am] = av.z; As[ak + 3][am] = av.w;
    *(float4*)&Bs[bk][bnc] = bv;
    __syncthreads();
#pragma unroll
    for (int kk = 0; kk < 16; ++kk) {
      float4 a4 = *(const float4*)&As[kk][ty * 4];
      float4 b4 = *(const float4*)&Bs[kk][tx * 4];
      float ar[4] = {a4.x, a4.y, a4.z, a4.w};
      float br[4] = {b4.x, b4.y, b4.z, b4.w};
#pragma unroll
      for (int i = 0; i < 4; ++i)
#pragma unroll
        for (int j = 0; j < 4; ++j) acc[i][j] += ar[i] * br[j];
    }
    __syncthreads();
  }
#pragma unroll
  for (int i = 0; i < 4; ++i) {
    int m = bm + ty * 4 + i;
    if (m >= M) continue;
#pragma unroll
    for (int j = 0; j < 4; ++j) {
      int n = bn + tx * 4 + j;
      if (n >= Nd) continue;
      float a = acc[i][j];
      if (emode == 0) {
        outF[(size_t)m * ldo + n] = a + bias[n];
      } else if (emode == 1) {
        outF[(size_t)m * ldo + n] = fmaxf(a + bias[n], 0.f);
      } else if (emode == 2) {
        outF[(size_t)m * ldo + n] = fmaxf(a + resid[(size_t)m * 128 + n], 0.f);
      } else if (emode == 3) {
        outF[(size_t)m * ldo + n] =
            (resid[(size_t)m * 128 + n] + a * red[2]) / anorm[m];
      } else if (emode == 4) {
        outF[(size_t)m * ldo + n] = a;
      } else {
        outF[(size_t)m * ldo + n] = 0.5f * a + bias[n];
      }
    }
  }
}

// ---------------- graph kernels ----------------
__global__ void count_kernel(const int* ei, int* deg, int E) {
  int e = blockIdx.x * blockDim.x + threadIdx.x;
  if (e >= E) return;
  atomicAdd(&deg[ei[E + e]], 1);  // in-degree over col
}

__global__ __launch_bounds__(256) void scan_kernel(const int* deg, int* start,
                                                   int* cursor, float* inv, int n) {
  __shared__ int part[256];
  int t = threadIdx.x;
  const int Cch = (n + 255) / 256;
  int lo = t * Cch, hi = min(n, lo + Cch);
  int s = 0;
  for (int i = lo; i < hi; ++i) s += deg[i];
  part[t] = s;
  __syncthreads();
  for (int off = 1; off < 256; off <<= 1) {
    int v = part[t];
    int add = (t >= off) ? part[t - off] : 0;
    __syncthreads();
    part[t] = v + add;
    __syncthreads();
  }
  int p = (t == 0) ? 0 : part[t - 1];
  for (int i = lo; i < hi; ++i) {
    start[i] = p; cursor[i] = p;
    int d = deg[i];
    inv[i] = (d > 0) ? rsqrtf((float)d) : 0.f;
    p += d;
  }
  if (t == 255) start[n] = part[255];
}

__global__ void fill_kernel(const int* ei, int* cursor, int* bucket, int E) {
  int e = blockIdx.x * blockDim.x + threadIdx.x;
  if (e >= E) return;
  int r = ei[e], c = ei[E + e];
  int pos = atomicAdd(&cursor[c], 1);
  bucket[pos] = r;
}

// agg[n,f] = inv[n] * sum_{edges into n} inv[row] * h[row,f]
__global__ __launch_bounds__(256) void gather_kernel(const float* h, const int* start,
                                                     const int* bucket, const float* inv,
                                                     float* agg, int n) {
  int node = blockIdx.x * 2 + (threadIdx.x >> 7);
  int f = threadIdx.x & 127;
  if (node >= n) return;
  int s0 = start[node], s1 = start[node + 1];
  float acc = 0.f;
  for (int j = s0; j < s1; ++j) {
    int r = bucket[j];
    acc += inv[r] * h[(size_t)r * HH + f];
  }
  agg[(size_t)node * HH + f] = inv[node] * acc;
}

// ---------------- small dense kernels ----------------
// env = softmax(h @ w[H,K] + b), K=4
__global__ __launch_bounds__(256) void env_softmax_kernel(const float* h, const float* w,
                                                          const float* b, float* env, int M) {
  __shared__ float ws[HH * KK];
  for (int i = threadIdx.x; i < HH * KK; i += blockDim.x) ws[i] = w[i];
  __syncthreads();
  int n = blockIdx.x * blockDim.x + threadIdx.x;
  if (n >= M) return;
  float l0 = b[0], l1 = b[1], l2 = b[2], l3 = b[3];
  const float* hp = h + (size_t)n * HH;
  for (int d = 0; d < HH; ++d) {
    float hv = hp[d];
    l0 += hv * ws[d * 4 + 0]; l1 += hv * ws[d * 4 + 1];
    l2 += hv * ws[d * 4 + 2]; l3 += hv * ws[d * 4 + 3];
  }
  float m = fmaxf(fmaxf(l0, l1), fmaxf(l2, l3));
  float e0 = __expf(l0 - m), e1 = __expf(l1 - m), e2 = __expf(l2 - m), e3 = __expf(l3 - m);
  float s = 1.f / (e0 + e1 + e2 + e3);
  float* o = env + (size_t)n * KK;
  o[0] = e0 * s; o[1] = e1 * s; o[2] = e2 * s; o[3] = e3 * s;
}

// colsum(k)->ksum[128]; sumsq(q)->red[0]; sumsq(k)->red[1]
__global__ __launch_bounds__(128) void colstats_kernel(const float* q, const float* k,
                                                       float* ksum, float* red, int n) {
  int t = threadIdx.x;
  const int ROWS = 512;
  int lo = blockIdx.x * ROWS, hi = min(n, lo + ROWS);
  float ks = 0.f, sq = 0.f, sk = 0.f;
  for (int r = lo; r < hi; ++r) {
    float kv = k[(size_t)r * HH + t];
    float qv = q[(size_t)r * HH + t];
    ks += kv; sq += qv * qv; sk += kv * kv;
  }
  atomicAdd(&ksum[t], ks);
  __shared__ float sh[2][128];
  sh[0][t] = sq; sh[1][t] = sk;
  __syncthreads();
  for (int off = 64; off > 0; off >>= 1) {
    if (t < off) { sh[0][t] += sh[0][t + off]; sh[1][t] += sh[1][t + off]; }
    __syncthreads();
  }
  if (t == 0) { atomicAdd(&red[0], sh[0][0]); atomicAdd(&red[1], sh[1][0]); }
}

// ktv[128,128] += k_chunk^T @ v_chunk
__global__ __launch_bounds__(256) void ktv_kernel(const float* k, const float* v,
                                                  float* ktv, int n) {
  __shared__ float ks[8][128], vs[8][128];
  const int CH = 512;
  int t = threadIdx.x;
  int ty = t >> 4, tx = t & 15;
  float acc[8][8];
#pragma unroll
  for (int i = 0; i < 8; ++i)
#pragma unroll
    for (int j = 0; j < 8; ++j) acc[i][j] = 0.f;
  int lo = blockIdx.x * CH, hi = min(n, lo + CH);
  for (int r0 = lo; r0 < hi; r0 += 8) {
    int nr = min(8, hi - r0);
    __syncthreads();
    for (int i = t; i < 8 * 128; i += 256) {
      int rr = i >> 7, cc = i & 127;
      float kv = 0.f, vv = 0.f;
      if (rr < nr) {
        kv = k[(size_t)(r0 + rr) * HH + cc];
        vv = v[(size_t)(r0 + rr) * HH + cc];
      }
      ks[rr][cc] = kv; vs[rr][cc] = vv;
    }
    __syncthreads();
#pragma unroll
    for (int rr = 0; rr < 8; ++rr) {
      float kr[8], vr[8];
#pragma unroll
      for (int i = 0; i < 8; ++i) kr[i] = ks[rr][ty * 8 + i];
#pragma unroll
      for (int j = 0; j < 8; ++j) vr[j] = vs[rr][tx * 8 + j];
#pragma unroll
      for (int i = 0; i < 8; ++i)
#pragma unroll
        for (int j = 0; j < 8; ++j) acc[i][j] += kr[i] * vr[j];
    }
  }
#pragma unroll
  for (int i = 0; i < 8; ++i)
#pragma unroll
    for (int j = 0; j < 8; ++j)
      atomicAdd(&ktv[(size_t)(ty * 8 + i) * HH + tx * 8 + j], acc[i][j]);
}

__global__ void scale_kernel(float* red, int n) {
  float nq = fmaxf(sqrtf(red[0]), 1e-12f);
  float nk = fmaxf(sqrtf(red[1]), 1e-12f);
  red[2] = 1.f / (nq * nk * (float)n);
}

// anorm[n] = max(1 + (q_raw . ksum_raw) * red[2], 1e-12)
__global__ __launch_bounds__(256) void anorm_kernel(const float* q, const float* ksum,
                                                    const float* red, float* anorm, int M) {
  __shared__ float ks[HH];
  for (int i = threadIdx.x; i < HH; i += blockDim.x) ks[i] = ksum[i];
  __syncthreads();
  int n = blockIdx.x * blockDim.x + threadIdx.x;
  if (n >= M) return;
  const float* qp = q + (size_t)n * HH;
  float d = 0.f;
  for (int i = 0; i < HH; ++i) d += qp[i] * ks[i];
  float a = 1.f + d * red[2];
  anorm[n] = fmaxf(a, 1e-12f);
}

// ---------------- host-side diagnostics (correctness call only; skipped under capture) ----
static int g_diag = 0;
static void dump_f(const char* tag, const void* dptr, size_t n_f, hipStream_t s) {
  if (!g_diag) return;
  float buf[2048];
  size_t n = n_f < 2048 ? n_f : 2048;
  hipMemcpyAsync(buf, dptr, n * 4, hipMemcpyDeviceToHost, s);
  hipStreamSynchronize(s);
  double am = 0, mean = 0;
  int nan = 0;
  for (size_t i = 0; i < n; ++i) {
    float v = buf[i];
    if (v != v) { ++nan; continue; }
    if (fabs(v) > am) am = fabs(v);
    mean += v;
  }
  fprintf(stderr, "[diag] %-8s first=[%.5g %.5g %.5g %.5g] absmax=%.5g mean=%.5g nan=%d/%zu\n",
          tag, buf[0], buf[1], buf[2], buf[3], am, mean / (double)n, nan, n);
  fflush(stderr);
}

// ---------------- host launcher ----------------
extern "C" void kernel_launch(void* const* d_in, const int* in_sizes, int n_in,
                              void* d_out, int out_size, void* d_ws, size_t ws_size,
                              hipStream_t stream) {
  hipStreamCaptureStatus cs = hipStreamCaptureStatusNone;
  hipStreamIsCapturing(stream, &cs);
  g_diag = (cs == hipStreamCaptureStatusNone);

  const float* x = (const float*)d_in[0];
  const int* ei = (const int*)d_in[1];
  const float* fc0_w = (const float*)d_in[2];
  const float* fc0_b = (const float*)d_in[3];
  const float* fc1_w = (const float*)d_in[4];
  const float* fc1_b = (const float*)d_in[5];
  const float* env_w = (const float*)d_in[6];
  const float* env_b = (const float*)d_in[7];
  const float* conv_w = (const float*)d_in[8];
  const float* q_w = (const float*)d_in[9];
  const float* q_b = (const float*)d_in[10];
  const float* k_w = (const float*)d_in[11];
  const float* k_b = (const float*)d_in[12];
  const float* v_w = (const float*)d_in[13];
  const float* v_b = (const float*)d_in[14];
  const float* envp_w = (const float*)d_in[15];
  const float* envp_b = (const float*)d_in[16];
  const float* genv_w = (const float*)d_in[17];
  const float* gt_w = (const float*)d_in[18];
  const float* gt_b = (const float*)d_in[19];
  float* out = (float*)d_out;

  const size_t NH = (size_t)NN * HH;
  float* W = (float*)d_ws;
  float* hA = W;             // final h
  float* hB = W + NH;        // layer buffer -> k -> ctx
  float* agg = W + 2 * NH;   // agg -> q
  float* vbuf = W + 3 * NH;  // v -> gh
  float* gr = W + 4 * NH;
  float* env = W + 5 * NH;
  float* genv = env + (size_t)NN * KK;
  float* inv = genv + (size_t)NN * KK;
  float* anorm = inv + NN;
  float* ksum = anorm + NN;
  float* red = ksum + HH;
  float* ktv = red + 4;
  int* deg = (int*)(ktv + (size_t)HH * HH);
  int* start = deg + NN;
  int* cursor = start + NN + 1;
  int* bucket = cursor + NN;

  float* q = agg;
  float* kb = hB;
  float* ctx = hB;
  float* gh = vbuf;

  dim3 b256(256);

  zero_i32_kernel<<<dim3((NN + 255) / 256), b256, 0, stream>>>(deg, NN);
  zero_f32_kernel<<<dim3((HH + 4 + HH * HH + 255) / 256), b256, 0, stream>>>(ksum, HH + 4 + HH * HH);

  // CSR build (verified R4: startN=800000, sane deg/inv)
  count_kernel<<<dim3((EE + 255) / 256), b256, 0, stream>>>(ei, deg, EE);
  scan_kernel<<<dim3(1), b256, 0, stream>>>(deg, start, cursor, inv, NN);
  fill_kernel<<<dim3((EE + 255) / 256), b256, 0, stream>>>(ei, cursor, bucket, EE);

  // fc0: h = relu(x @ fc0_w + b)
  gemm_kernel<<<dim3((NN + 63) / 64, 2), b256, 0, stream>>>(
      1, x, nullptr, nullptr, DD, fc0_w, HH,
      1, hA, HH, fc0_b, nullptr, nullptr, nullptr, NN, HH, DD);
  dump_f("h_fc0", hA, 2048, stream);

  // conv layers
  float* hcur = hA;
  float* hnext = hB;
  for (int l = 0; l < 2; ++l) {
    env_softmax_kernel<<<dim3((NN + 255) / 256), b256, 0, stream>>>(
        hcur, env_w + (size_t)l * HH * KK, env_b + (size_t)l * KK, env, NN);
    gather_kernel<<<dim3((NN + 1) / 2), b256, 0, stream>>>(hcur, start, bucket, inv, agg, NN);
    gemm_kernel<<<dim3((NN + 63) / 64, 2), b256, 0, stream>>>(
        2, agg, hcur, env, HH, conv_w + (size_t)l * KK * 2 * HH * HH, HH,
        2, hnext, HH, nullptr, hcur, nullptr, nullptr, NN, HH, KK * 2 * HH);
    float* t = hcur; hcur = hnext; hnext = t;
  }
  dump_f("h_conv1", hcur, 2048, stream);

  // q, k, v
  gemm_kernel<<<dim3((NN + 63) / 64, 2), b256, 0, stream>>>(
      1, hcur, nullptr, nullptr, HH, q_w, HH,
      0, q, HH, q_b, nullptr, nullptr, nullptr, NN, HH, HH);
  gemm_kernel<<<dim3((NN + 63) / 64, 2), b256, 0, stream>>>(
      1, hcur, nullptr, nullptr, HH, k_w, HH,
      0, kb, HH, k_b, nullptr, nullptr, nullptr, NN, HH, HH);
  gemm_kernel<<<dim3((NN + 63) / 64, 2), b256, 0, stream>>>(
      1, hcur, nullptr, nullptr, HH, v_w, HH,
      0, vbuf, HH, v_b, nullptr, nullptr, nullptr, NN, HH, HH);

  colstats_kernel<<<dim3((NN + 511) / 512), dim3(128), 0, stream>>>(q, kb, ksum, red, NN);
  ktv_kernel<<<dim3((NN + 511) / 512), b256, 0, stream>>>(kb, vbuf, ktv, NN);
  scale_kernel<<<dim3(1), dim3(1), 0, stream>>>(red, NN);
  anorm_kernel<<<dim3((NN + 255) / 256), b256, 0, stream>>>(q, ksum, red, anorm, NN);
  dump_f("anorm", anorm, 64, stream);

  // gr = (v + q @ ktv * red[2]) / anorm
  gemm_kernel<<<dim3((NN + 63) / 64, 2), b256, 0, stream>>>(
      1, q, nullptr, nullptr, HH, ktv, HH,
      3, gr, HH, nullptr, vbuf, anorm, red, NN, HH, HH);
  dump_f("gr", gr, 2048, stream);

  // genv = softmax(gr @ envp_w + envp_b)
  env_softmax_kernel<<<dim3((NN + 255) / 256), b256, 0, stream>>>(gr, envp_w, envp_b, genv, NN);

  // ctx = sum_k genv[:,k] * (gr @ genv_w[k])
  gemm_kernel<<<dim3((NN + 63) / 64, 2), b256, 0, stream>>>(
      3, gr, nullptr, genv, HH, genv_w, HH,
      4, ctx, HH, nullptr, nullptr, nullptr, nullptr, NN, HH, KK * HH);

  // gh = relu(ctx @ gt_w + gt_b)
  gemm_kernel<<<dim3((NN + 63) / 64, 2), b256, 0, stream>>>(
      1, ctx, nullptr, nullptr, HH, gt_w, HH,
      1, gh, HH, gt_b, nullptr, nullptr, nullptr, NN, HH, HH);

  // out = 0.5*((h+gh) @ fc1_w) + fc1_b   (f32 output)
  gemm_kernel<<<dim3((NN + 63) / 64, 1), b256, 0, stream>>>(
      4, hcur, gh, nullptr, HH, fc1_w, CC,
      5, out, CC, fc1_b, nullptr, nullptr, nullptr, NN, CC, HH);
  dump_f("out", out, 64, stream);
}

// Round 6
// 1438.678 us; speedup vs baseline: 1.2773x; 1.2773x over previous
//
#include <hip/hip_runtime.h>

#define DEV __device__ __forceinline__

static constexpr int NN = 50000;   // nodes
static constexpr int DD = 256;     // input dim
static constexpr int HH = 128;     // hidden
static constexpr int CC = 40;      // classes
static constexpr int KK = 4;       // envs
static constexpr int EE = 800000;  // edges

typedef __attribute__((ext_vector_type(8))) short bf16x8;
typedef __attribute__((ext_vector_type(4))) float f32x4;

DEV unsigned short f2bf(float f) {
  union { float f; unsigned int i; } c; c.f = f;
  unsigned int x = c.i;
  x += 0x7FFFu + ((x >> 16) & 1u);   // round-to-nearest-even
  return (unsigned short)(x >> 16);
}

// harness-named kernel (unused in pipeline)
__global__ void MLEI_12970801234193_kernel(float* out, int n) {
  int i = blockIdx.x * blockDim.x + threadIdx.x;
  if (i < n) out[i] = 7.0f;
}

__global__ void zero_i32_kernel(int* p, int n) {
  int i = blockIdx.x * blockDim.x + threadIdx.x;
  if (i < n) p[i] = 0;
}
__global__ void zero_f32_kernel(float* p, int n) {
  int i = blockIdx.x * blockDim.x + threadIdx.x;
  if (i < n) p[i] = 0.f;
}

// transpose-convert: dst[m][n][k] = bf16(src[m][k][n]); nm matrices of K x N
__global__ void tcvt_kernel(const float* __restrict__ src, unsigned short* __restrict__ dst,
                            int K, int N, int nm) {
  int i = blockIdx.x * blockDim.x + threadIdx.x;
  int tot = nm * K * N;
  if (i >= tot) return;
  int m = i / (K * N);
  int rem = i - m * K * N;
  int k = rem / N;
  int n = rem - k * N;
  dst[(size_t)m * K * N + (size_t)n * K + k] = f2bf(src[i]);
}

// ---------------- generic bf16-MFMA GEMM ----------------
// C[M,Nd] = A[M,K] (+Aadd) @ B[K,Nd]; Bt is bf16 [n][k] row-major (ldk=K).
// block = 256 thr = 4 waves (2x2), tile 128m x 128n; K multiple of 32; Nd <= 128.
// emode: 0 acc+bias | 1 relu(acc+bias) | 3 (resid+acc*red[2])/anorm[row] | 5 0.5*acc+bias
__global__ __launch_bounds__(256) void mgemm_kernel(
    const float* __restrict__ A, const float* __restrict__ Aadd, int lda,
    const unsigned short* __restrict__ Bt, int K,
    int emode, float* __restrict__ out, int ldo,
    const float* __restrict__ bias, const float* __restrict__ resid, int ldr,
    const float* __restrict__ anorm, const float* __restrict__ red,
    int M, int Nd) {
  __shared__ unsigned short As[128][40];  // [m][k] pad->40 (80B rows, 16B aligned)
  __shared__ unsigned short Bs[128][40];  // [n][k]
  const int tid = threadIdx.x, lane = tid & 63, wave = tid >> 6;
  const int quad = lane >> 4, l16 = lane & 15;
  const int wm = (wave >> 1) * 64, wn = (wave & 1) * 64;
  const int bm = blockIdx.x * 128;
  const int srow = tid >> 1, skh = (tid & 1) * 16;

  f32x4 acc[4][4];
#pragma unroll
  for (int i = 0; i < 4; ++i)
#pragma unroll
    for (int j = 0; j < 4; ++j)
#pragma unroll
      for (int r = 0; r < 4; ++r) acc[i][j][r] = 0.f;

  for (int k0 = 0; k0 < K; k0 += 32) {
    // ---- stage A (f32 -> bf16) ----
    {
      int grow = bm + srow;
      float va[16];
      if (grow < M) {
        const float* ap = A + (size_t)grow * lda + k0 + skh;
        float4 v0 = *(const float4*)(ap + 0), v1 = *(const float4*)(ap + 4);
        float4 v2 = *(const float4*)(ap + 8), v3 = *(const float4*)(ap + 12);
        va[0] = v0.x; va[1] = v0.y; va[2] = v0.z; va[3] = v0.w;
        va[4] = v1.x; va[5] = v1.y; va[6] = v1.z; va[7] = v1.w;
        va[8] = v2.x; va[9] = v2.y; va[10] = v2.z; va[11] = v2.w;
        va[12] = v3.x; va[13] = v3.y; va[14] = v3.z; va[15] = v3.w;
        if (Aadd) {
          const float* ap2 = Aadd + (size_t)grow * lda + k0 + skh;
          float4 w0 = *(const float4*)(ap2 + 0), w1 = *(const float4*)(ap2 + 4);
          float4 w2 = *(const float4*)(ap2 + 8), w3 = *(const float4*)(ap2 + 12);
          va[0] += w0.x; va[1] += w0.y; va[2] += w0.z; va[3] += w0.w;
          va[4] += w1.x; va[5] += w1.y; va[6] += w1.z; va[7] += w1.w;
          va[8] += w2.x; va[9] += w2.y; va[10] += w2.z; va[11] += w2.w;
          va[12] += w3.x; va[13] += w3.y; va[14] += w3.z; va[15] += w3.w;
        }
      } else {
#pragma unroll
        for (int z = 0; z < 16; ++z) va[z] = 0.f;
      }
      bf16x8 p0, p1;
#pragma unroll
      for (int z = 0; z < 8; ++z) { p0[z] = (short)f2bf(va[z]); p1[z] = (short)f2bf(va[z + 8]); }
      *(bf16x8*)&As[srow][skh] = p0;
      *(bf16x8*)&As[srow][skh + 8] = p1;
      // ---- stage B (bf16 copy) ----
      bf16x8 b0, b1;
      if (srow < Nd) {
        const unsigned short* bp = Bt + (size_t)srow * K + k0 + skh;
        b0 = *(const bf16x8*)(bp);
        b1 = *(const bf16x8*)(bp + 8);
      } else {
#pragma unroll
        for (int z = 0; z < 8; ++z) { b0[z] = 0; b1[z] = 0; }
      }
      *(bf16x8*)&Bs[srow][skh] = b0;
      *(bf16x8*)&Bs[srow][skh + 8] = b1;
    }
    __syncthreads();
    bf16x8 af[4], bfr[4];
#pragma unroll
    for (int i = 0; i < 4; ++i) af[i] = *(const bf16x8*)&As[wm + i * 16 + l16][quad * 8];
#pragma unroll
    for (int j = 0; j < 4; ++j) bfr[j] = *(const bf16x8*)&Bs[wn + j * 16 + l16][quad * 8];
#pragma unroll
    for (int i = 0; i < 4; ++i)
#pragma unroll
      for (int j = 0; j < 4; ++j)
        acc[i][j] = __builtin_amdgcn_mfma_f32_16x16x32_bf16(af[i], bfr[j], acc[i][j], 0, 0, 0);
    __syncthreads();
  }

  float s2 = (emode == 3) ? red[2] : 0.f;
#pragma unroll
  for (int j = 0; j < 4; ++j) {
    int col = wn + j * 16 + l16;
    if (col >= Nd) continue;
    float bv = bias ? bias[col] : 0.f;
#pragma unroll
    for (int i = 0; i < 4; ++i) {
#pragma unroll
      for (int r = 0; r < 4; ++r) {
        int row = bm + wm + i * 16 + quad * 4 + r;
        if (row >= M) continue;
        float a = acc[i][j][r];
        float o;
        if (emode == 0) o = a + bv;
        else if (emode == 1) o = fmaxf(a + bv, 0.f);
        else if (emode == 3) o = (resid[(size_t)row * ldr + col] + a * s2) / anorm[row];
        else o = 0.5f * a + bv;
        out[(size_t)row * ldo + col] = o;
      }
    }
  }
}

// ---------------- env-weighted MFMA GEMM (conv & ctx) ----------------
// out[m,n] = epi( sum_e env[m,e] * (Ae @ Bt_e)[m,n] ), Ae = [A1;A2] (Kpe cols) or A1.
// Btc: bf16 [e][128][Kpe] (n-major rows). relu_resid: 1 -> relu(acc+resid), 0 -> plain.
__global__ __launch_bounds__(256) void mconv_kernel(
    const float* __restrict__ A1, const float* __restrict__ A2,
    const float* __restrict__ env, const unsigned short* __restrict__ Btc, int Kpe,
    int relu_resid, const float* __restrict__ resid, float* __restrict__ out, int M) {
  __shared__ unsigned short As[128][40];
  __shared__ unsigned short Bs[128][40];
  __shared__ float envs[128][4];
  const int tid = threadIdx.x, lane = tid & 63, wave = tid >> 6;
  const int quad = lane >> 4, l16 = lane & 15;
  const int wm = (wave >> 1) * 64, wn = (wave & 1) * 64;
  const int bm = blockIdx.x * 128;
  const int srow = tid >> 1, skh = (tid & 1) * 16;

  for (int i = tid; i < 512; i += 256) {
    int r = i >> 2, c = i & 3;
    int g = bm + r;
    envs[r][c] = (g < M) ? env[(size_t)g * 4 + c] : 0.f;
  }

  f32x4 acc[4][4];
#pragma unroll
  for (int i = 0; i < 4; ++i)
#pragma unroll
    for (int j = 0; j < 4; ++j)
#pragma unroll
      for (int r = 0; r < 4; ++r) acc[i][j][r] = 0.f;

  const int nch = Kpe >> 5;
  for (int e = 0; e < 4; ++e) {
    f32x4 p[4][4];
#pragma unroll
    for (int i = 0; i < 4; ++i)
#pragma unroll
      for (int j = 0; j < 4; ++j)
#pragma unroll
        for (int r = 0; r < 4; ++r) p[i][j][r] = 0.f;

    for (int kc = 0; kc < nch; ++kc) {
      int kof = kc * 32;
      const float* Asrc = A1;
      int ks = kof;
      if (A2 && kof >= 128) { Asrc = A2; ks = kof - 128; }
      {
        int grow = bm + srow;
        float va[16];
        if (grow < M) {
          const float* ap = Asrc + (size_t)grow * 128 + ks + skh;
          float4 v0 = *(const float4*)(ap + 0), v1 = *(const float4*)(ap + 4);
          float4 v2 = *(const float4*)(ap + 8), v3 = *(const float4*)(ap + 12);
          va[0] = v0.x; va[1] = v0.y; va[2] = v0.z; va[3] = v0.w;
          va[4] = v1.x; va[5] = v1.y; va[6] = v1.z; va[7] = v1.w;
          va[8] = v2.x; va[9] = v2.y; va[10] = v2.z; va[11] = v2.w;
          va[12] = v3.x; va[13] = v3.y; va[14] = v3.z; va[15] = v3.w;
        } else {
#pragma unroll
          for (int z = 0; z < 16; ++z) va[z] = 0.f;
        }
        bf16x8 p0, p1;
#pragma unroll
        for (int z = 0; z < 8; ++z) { p0[z] = (short)f2bf(va[z]); p1[z] = (short)f2bf(va[z + 8]); }
        *(bf16x8*)&As[srow][skh] = p0;
        *(bf16x8*)&As[srow][skh + 8] = p1;
        const unsigned short* bp = Btc + ((size_t)e * 128 + srow) * Kpe + kof + skh;
        bf16x8 b0 = *(const bf16x8*)(bp);
        bf16x8 b1 = *(const bf16x8*)(bp + 8);
        *(bf16x8*)&Bs[srow][skh] = b0;
        *(bf16x8*)&Bs[srow][skh + 8] = b1;
      }
      __syncthreads();
      bf16x8 af[4], bfr[4];
#pragma unroll
      for (int i = 0; i < 4; ++i) af[i] = *(const bf16x8*)&As[wm + i * 16 + l16][quad * 8];
#pragma unroll
      for (int j = 0; j < 4; ++j) bfr[j] = *(const bf16x8*)&Bs[wn + j * 16 + l16][quad * 8];
#pragma unroll
      for (int i = 0; i < 4; ++i)
#pragma unroll
        for (int j = 0; j < 4; ++j)
          p[i][j] = __builtin_amdgcn_mfma_f32_16x16x32_bf16(af[i], bfr[j], p[i][j], 0, 0, 0);
      __syncthreads();
    }
    // fold env
#pragma unroll
    for (int i = 0; i < 4; ++i) {
      float ev[4];
#pragma unroll
      for (int r = 0; r < 4; ++r) ev[r] = envs[wm + i * 16 + quad * 4 + r][e];
#pragma unroll
      for (int j = 0; j < 4; ++j)
#pragma unroll
        for (int r = 0; r < 4; ++r) acc[i][j][r] += ev[r] * p[i][j][r];
    }
  }

#pragma unroll
  for (int j = 0; j < 4; ++j) {
    int col = wn + j * 16 + l16;
#pragma unroll
    for (int i = 0; i < 4; ++i) {
#pragma unroll
      for (int r = 0; r < 4; ++r) {
        int row = bm + wm + i * 16 + quad * 4 + r;
        if (row >= M) continue;
        float a = acc[i][j][r];
        float o = relu_resid ? fmaxf(a + resid[(size_t)row * 128 + col], 0.f) : a;
        out[(size_t)row * 128 + col] = o;
      }
    }
  }
}

// ---------------- graph kernels (unchanged, verified R4/R5) ----------------
__global__ void count_kernel(const int* ei, int* deg, int E) {
  int e = blockIdx.x * blockDim.x + threadIdx.x;
  if (e >= E) return;
  atomicAdd(&deg[ei[E + e]], 1);
}

__global__ __launch_bounds__(256) void scan_kernel(const int* deg, int* start,
                                                   int* cursor, float* inv, int n) {
  __shared__ int part[256];
  int t = threadIdx.x;
  const int Cch = (n + 255) / 256;
  int lo = t * Cch, hi = min(n, lo + Cch);
  int s = 0;
  for (int i = lo; i < hi; ++i) s += deg[i];
  part[t] = s;
  __syncthreads();
  for (int off = 1; off < 256; off <<= 1) {
    int v = part[t];
    int add = (t >= off) ? part[t - off] : 0;
    __syncthreads();
    part[t] = v + add;
    __syncthreads();
  }
  int p = (t == 0) ? 0 : part[t - 1];
  for (int i = lo; i < hi; ++i) {
    start[i] = p; cursor[i] = p;
    int d = deg[i];
    inv[i] = (d > 0) ? rsqrtf((float)d) : 0.f;
    p += d;
  }
  if (t == 255) start[n] = part[255];
}

__global__ void fill_kernel(const int* ei, int* cursor, int* bucket, int E) {
  int e = blockIdx.x * blockDim.x + threadIdx.x;
  if (e >= E) return;
  int r = ei[e], c = ei[E + e];
  int pos = atomicAdd(&cursor[c], 1);
  bucket[pos] = r;
}

__global__ __launch_bounds__(256) void gather_kernel(const float* h, const int* start,
                                                     const int* bucket, const float* inv,
                                                     float* agg, int n) {
  int node = blockIdx.x * 2 + (threadIdx.x >> 7);
  int f = threadIdx.x & 127;
  if (node >= n) return;
  int s0 = start[node], s1 = start[node + 1];
  float acc = 0.f;
  for (int j = s0; j < s1; ++j) {
    int r = bucket[j];
    acc += inv[r] * h[(size_t)r * HH + f];
  }
  agg[(size_t)node * HH + f] = inv[node] * acc;
}

// ---------------- env softmax (LDS-staged, coalesced) ----------------
__global__ __launch_bounds__(256) void env_softmax_kernel(const float* __restrict__ h,
                                                          const float* __restrict__ w,
                                                          const float* __restrict__ b,
                                                          float* __restrict__ env, int M) {
  __shared__ float hs[64][129];
  __shared__ float ws[HH * KK];
  int tid = threadIdx.x;
  int base = blockIdx.x * 64;
  for (int i = tid; i < HH * KK; i += 256) ws[i] = w[i];
  {
    int row = tid >> 2, q4 = (tid & 3) * 32;
    int g = base + row;
    if (g < M) {
      const float* hp = h + (size_t)g * HH + q4;
#pragma unroll
      for (int z = 0; z < 8; ++z) {
        float4 v = *(const float4*)(hp + z * 4);
        hs[row][q4 + z * 4 + 0] = v.x; hs[row][q4 + z * 4 + 1] = v.y;
        hs[row][q4 + z * 4 + 2] = v.z; hs[row][q4 + z * 4 + 3] = v.w;
      }
    }
  }
  __syncthreads();
  if (tid < 64 && base + tid < M) {
    float l0 = b[0], l1 = b[1], l2 = b[2], l3 = b[3];
    for (int d = 0; d < HH; ++d) {
      float hv = hs[tid][d];
      l0 += hv * ws[d * 4 + 0]; l1 += hv * ws[d * 4 + 1];
      l2 += hv * ws[d * 4 + 2]; l3 += hv * ws[d * 4 + 3];
    }
    float m = fmaxf(fmaxf(l0, l1), fmaxf(l2, l3));
    float e0 = __expf(l0 - m), e1 = __expf(l1 - m), e2 = __expf(l2 - m), e3 = __expf(l3 - m);
    float s = 1.f / (e0 + e1 + e2 + e3);
    *(float4*)(env + (size_t)(base + tid) * KK) = make_float4(e0 * s, e1 * s, e2 * s, e3 * s);
  }
}

// ---------------- linear-transformer reductions (unchanged) ----------------
__global__ __launch_bounds__(128) void colstats_kernel(const float* q, const float* k,
                                                       float* ksum, float* red, int n) {
  int t = threadIdx.x;
  const int ROWS = 512;
  int lo = blockIdx.x * ROWS, hi = min(n, lo + ROWS);
  float ks = 0.f, sq = 0.f, sk = 0.f;
  for (int r = lo; r < hi; ++r) {
    float kv = k[(size_t)r * HH + t];
    float qv = q[(size_t)r * HH + t];
    ks += kv; sq += qv * qv; sk += kv * kv;
  }
  atomicAdd(&ksum[t], ks);
  __shared__ float sh[2][128];
  sh[0][t] = sq; sh[1][t] = sk;
  __syncthreads();
  for (int off = 64; off > 0; off >>= 1) {
    if (t < off) { sh[0][t] += sh[0][t + off]; sh[1][t] += sh[1][t + off]; }
    __syncthreads();
  }
  if (t == 0) { atomicAdd(&red[0], sh[0][0]); atomicAdd(&red[1], sh[1][0]); }
}

__global__ __launch_bounds__(256) void ktv_kernel(const float* k, const float* v,
                                                  float* ktv, int n) {
  __shared__ float ks[8][128], vs[8][128];
  const int CH = 512;
  int t = threadIdx.x;
  int ty = t >> 4, tx = t & 15;
  float acc[8][8];
#pragma unroll
  for (int i = 0; i < 8; ++i)
#pragma unroll
    for (int j = 0; j < 8; ++j) acc[i][j] = 0.f;
  int lo = blockIdx.x * CH, hi = min(n, lo + CH);
  for (int r0 = lo; r0 < hi; r0 += 8) {
    int nr = min(8, hi - r0);
    __syncthreads();
    for (int i = t; i < 8 * 128; i += 256) {
      int rr = i >> 7, cc = i & 127;
      float kv = 0.f, vv = 0.f;
      if (rr < nr) {
        kv = k[(size_t)(r0 + rr) * HH + cc];
        vv = v[(size_t)(r0 + rr) * HH + cc];
      }
      ks[rr][cc] = kv; vs[rr][cc] = vv;
    }
    __syncthreads();
#pragma unroll
    for (int rr = 0; rr < 8; ++rr) {
      float kr[8], vr[8];
#pragma unroll
      for (int i = 0; i < 8; ++i) kr[i] = ks[rr][ty * 8 + i];
#pragma unroll
      for (int j = 0; j < 8; ++j) vr[j] = vs[rr][tx * 8 + j];
#pragma unroll
      for (int i = 0; i < 8; ++i)
#pragma unroll
        for (int j = 0; j < 8; ++j) acc[i][j] += kr[i] * vr[j];
    }
  }
#pragma unroll
  for (int i = 0; i < 8; ++i)
#pragma unroll
    for (int j = 0; j < 8; ++j)
      atomicAdd(&ktv[(size_t)(ty * 8 + i) * HH + tx * 8 + j], acc[i][j]);
}

__global__ void scale_kernel(float* red, int n) {
  float nq = fmaxf(sqrtf(red[0]), 1e-12f);
  float nk = fmaxf(sqrtf(red[1]), 1e-12f);
  red[2] = 1.f / (nq * nk * (float)n);
}

__global__ __launch_bounds__(256) void anorm_kernel(const float* q, const float* ksum,
                                                    const float* red, float* anorm, int M) {
  __shared__ float ks[HH];
  for (int i = threadIdx.x; i < HH; i += blockDim.x) ks[i] = ksum[i];
  __syncthreads();
  int n = blockIdx.x * blockDim.x + threadIdx.x;
  if (n >= M) return;
  const float* qp = q + (size_t)n * HH;
  float d = 0.f;
  for (int i = 0; i < HH; ++i) d += qp[i] * ks[i];
  float a = 1.f + d * red[2];
  anorm[n] = fmaxf(a, 1e-12f);
}

// ---------------- host launcher ----------------
extern "C" void kernel_launch(void* const* d_in, const int* in_sizes, int n_in,
                              void* d_out, int out_size, void* d_ws, size_t ws_size,
                              hipStream_t stream) {
  const float* x = (const float*)d_in[0];
  const int* ei = (const int*)d_in[1];
  const float* fc0_w = (const float*)d_in[2];
  const float* fc0_b = (const float*)d_in[3];
  const float* fc1_w = (const float*)d_in[4];
  const float* fc1_b = (const float*)d_in[5];
  const float* env_w = (const float*)d_in[6];
  const float* env_b = (const float*)d_in[7];
  const float* conv_w = (const float*)d_in[8];
  const float* q_w = (const float*)d_in[9];
  const float* q_b = (const float*)d_in[10];
  const float* k_w = (const float*)d_in[11];
  const float* k_b = (const float*)d_in[12];
  const float* v_w = (const float*)d_in[13];
  const float* v_b = (const float*)d_in[14];
  const float* envp_w = (const float*)d_in[15];
  const float* envp_b = (const float*)d_in[16];
  const float* genv_w = (const float*)d_in[17];
  const float* gt_w = (const float*)d_in[18];
  const float* gt_b = (const float*)d_in[19];
  float* out = (float*)d_out;

  const size_t NH = (size_t)NN * HH;
  float* W = (float*)d_ws;
  float* hA = W;             // final h
  float* hB = W + NH;        // layer buffer -> k -> ctx
  float* agg = W + 2 * NH;   // agg -> q
  float* vbuf = W + 3 * NH;  // v -> gh
  float* gr = W + 4 * NH;
  float* env = W + 5 * NH;
  float* genv = env + (size_t)NN * KK;
  float* inv = genv + (size_t)NN * KK;
  float* anorm = inv + NN;
  float* ksum = anorm + NN;
  float* red = ksum + HH;
  float* ktv = red + 4;
  int* deg = (int*)(ktv + (size_t)HH * HH);
  int* start = deg + NN;
  int* cursor = start + NN + 1;
  int* bucket = cursor + NN;
  unsigned short* wb = (unsigned short*)(((uintptr_t)(bucket + EE) + 15) & ~(uintptr_t)15);
  unsigned short* Btfc0 = wb;                 // 256*128
  unsigned short* Btq = Btfc0 + 32768;        // 128*128
  unsigned short* Btk = Btq + 16384;
  unsigned short* Btv = Btk + 16384;
  unsigned short* Btgt = Btv + 16384;
  unsigned short* Btfc1 = Btgt + 16384;       // 40*128
  unsigned short* Btconv = Btfc1 + 5120;      // 2*4*128*256
  unsigned short* Btgenv = Btconv + 262144;   // 4*128*128
  unsigned short* Btktv = Btgenv + 65536;     // 128*128

  float* q = agg;
  float* kb = hB;
  float* ctx = hB;
  float* gh = vbuf;

  dim3 b256(256);
  const int MB = (NN + 127) / 128;  // 391

  zero_i32_kernel<<<dim3((NN + 255) / 256), b256, 0, stream>>>(deg, NN);
  zero_f32_kernel<<<dim3((HH + 4 + HH * HH + 255) / 256), b256, 0, stream>>>(ksum, HH + 4 + HH * HH);

  // CSR build
  count_kernel<<<dim3((EE + 255) / 256), b256, 0, stream>>>(ei, deg, EE);
  scan_kernel<<<dim3(1), b256, 0, stream>>>(deg, start, cursor, inv, NN);
  fill_kernel<<<dim3((EE + 255) / 256), b256, 0, stream>>>(ei, cursor, bucket, EE);

  // weight prep: transpose+bf16
  tcvt_kernel<<<dim3((32768 + 255) / 256), b256, 0, stream>>>(fc0_w, Btfc0, 256, 128, 1);
  tcvt_kernel<<<dim3((16384 + 255) / 256), b256, 0, stream>>>(q_w, Btq, 128, 128, 1);
  tcvt_kernel<<<dim3((16384 + 255) / 256), b256, 0, stream>>>(k_w, Btk, 128, 128, 1);
  tcvt_kernel<<<dim3((16384 + 255) / 256), b256, 0, stream>>>(v_w, Btv, 128, 128, 1);
  tcvt_kernel<<<dim3((16384 + 255) / 256), b256, 0, stream>>>(gt_w, Btgt, 128, 128, 1);
  tcvt_kernel<<<dim3((5120 + 255) / 256), b256, 0, stream>>>(fc1_w, Btfc1, 128, 40, 1);
  tcvt_kernel<<<dim3((262144 + 255) / 256), b256, 0, stream>>>(conv_w, Btconv, 256, 128, 8);
  tcvt_kernel<<<dim3((65536 + 255) / 256), b256, 0, stream>>>(genv_w, Btgenv, 128, 128, 4);

  // fc0: h = relu(x @ fc0_w + b)
  mgemm_kernel<<<dim3(MB), b256, 0, stream>>>(
      x, nullptr, DD, Btfc0, 256, 1, hA, HH, fc0_b, nullptr, 0, nullptr, nullptr, NN, HH);

  // conv layers
  float* hcur = hA;
  float* hnext = hB;
  for (int l = 0; l < 2; ++l) {
    env_softmax_kernel<<<dim3((NN + 63) / 64), b256, 0, stream>>>(
        hcur, env_w + (size_t)l * HH * KK, env_b + (size_t)l * KK, env, NN);
    gather_kernel<<<dim3((NN + 1) / 2), b256, 0, stream>>>(hcur, start, bucket, inv, agg, NN);
    mconv_kernel<<<dim3(MB), b256, 0, stream>>>(
        agg, hcur, env, Btconv + (size_t)l * 131072, 256, 1, hcur, hnext, NN);
    float* t = hcur; hcur = hnext; hnext = t;
  }
  // hcur == hA

  // q, k, v
  mgemm_kernel<<<dim3(MB), b256, 0, stream>>>(
      hcur, nullptr, HH, Btq, 128, 0, q, HH, q_b, nullptr, 0, nullptr, nullptr, NN, HH);
  mgemm_kernel<<<dim3(MB), b256, 0, stream>>>(
      hcur, nullptr, HH, Btk, 128, 0, kb, HH, k_b, nullptr, 0, nullptr, nullptr, NN, HH);
  mgemm_kernel<<<dim3(MB), b256, 0, stream>>>(
      hcur, nullptr, HH, Btv, 128, 0, vbuf, HH, v_b, nullptr, 0, nullptr, nullptr, NN, HH);

  colstats_kernel<<<dim3((NN + 511) / 512), dim3(128), 0, stream>>>(q, kb, ksum, red, NN);
  ktv_kernel<<<dim3((NN + 511) / 512), b256, 0, stream>>>(kb, vbuf, ktv, NN);
  scale_kernel<<<dim3(1), dim3(1), 0, stream>>>(red, NN);
  anorm_kernel<<<dim3((NN + 255) / 256), b256, 0, stream>>>(q, ksum, red, anorm, NN);
  tcvt_kernel<<<dim3((16384 + 255) / 256), b256, 0, stream>>>(ktv, Btktv, 128, 128, 1);

  // gr = (v + q @ ktv * red[2]) / anorm
  mgemm_kernel<<<dim3(MB), b256, 0, stream>>>(
      q, nullptr, HH, Btktv, 128, 3, gr, HH, nullptr, vbuf, HH, anorm, red, NN, HH);

  // genv = softmax(gr @ envp_w + envp_b)
  env_softmax_kernel<<<dim3((NN + 63) / 64), b256, 0, stream>>>(gr, envp_w, envp_b, genv, NN);

  // ctx = sum_k genv[:,k] * (gr @ genv_w[k])
  mconv_kernel<<<dim3(MB), b256, 0, stream>>>(
      gr, nullptr, genv, Btgenv, 128, 0, nullptr, ctx, NN);

  // gh = relu(ctx @ gt_w + gt_b)
  mgemm_kernel<<<dim3(MB), b256, 0, stream>>>(
      ctx, nullptr, HH, Btgt, 128, 1, gh, HH, gt_b, nullptr, 0, nullptr, nullptr, NN, HH);

  // out = 0.5*((h+gh) @ fc1_w) + fc1_b
  mgemm_kernel<<<dim3(MB), b256, 0, stream>>>(
      hcur, gh, HH, Btfc1, 128, 5, out, CC, fc1_b, nullptr, 0, nullptr, nullptr, NN, CC);
}

// Round 7
// 1254.805 us; speedup vs baseline: 1.4645x; 1.1465x over previous
//
#include <hip/hip_runtime.h>

#define DEV __device__ __forceinline__

static constexpr int NN = 50000;   // nodes
static constexpr int DD = 256;     // input dim
static constexpr int HH = 128;     // hidden
static constexpr int CC = 40;      // classes
static constexpr int KK = 4;       // envs
static constexpr int EE = 800000;  // edges
static constexpr int MP = 50176;   // padded node count (196*256, mult of 32)
static constexpr int SKV = 196;    // split-K blocks for ktv
static constexpr int CPB = 8;      // 32-node chunks per ktv block (196*8*32 = 50176)

typedef __attribute__((ext_vector_type(8))) short bf16x8;
typedef __attribute__((ext_vector_type(4))) float f32x4;

DEV unsigned short f2bf(float f) {
  union { float f; unsigned int i; } c; c.f = f;
  unsigned int x = c.i;
  x += 0x7FFFu + ((x >> 16) & 1u);   // round-to-nearest-even
  return (unsigned short)(x >> 16);
}

// harness-named kernel (unused in pipeline)
__global__ void MLEI_12970801234193_kernel(float* out, int n) {
  int i = blockIdx.x * blockDim.x + threadIdx.x;
  if (i < n) out[i] = 7.0f;
}

__global__ void zero_i32_kernel(int* p, int n) {
  int i = blockIdx.x * blockDim.x + threadIdx.x;
  if (i < n) p[i] = 0;
}
__global__ void zero_f32_kernel(float* p, int n) {
  int i = blockIdx.x * blockDim.x + threadIdx.x;
  if (i < n) p[i] = 0.f;
}

// zero the pad columns [NN, MP) of the transposed bf16 k/v buffers
__global__ void padzero_kernel(unsigned short* kT, unsigned short* vT) {
  int i = blockIdx.x * blockDim.x + threadIdx.x;
  const int PW = MP - NN;  // 176
  if (i >= HH * PW) return;
  int f = i / PW, c = i - f * PW;
  kT[(size_t)f * MP + NN + c] = 0;
  vT[(size_t)f * MP + NN + c] = 0;
}

// transpose-convert: dst[m][n][k] = bf16(src[m][k][n]); nm matrices of K x N
__global__ void tcvt_kernel(const float* __restrict__ src, unsigned short* __restrict__ dst,
                            int K, int N, int nm) {
  int i = blockIdx.x * blockDim.x + threadIdx.x;
  int tot = nm * K * N;
  if (i >= tot) return;
  int m = i / (K * N);
  int rem = i - m * K * N;
  int k = rem / N;
  int n = rem - k * N;
  dst[(size_t)m * K * N + (size_t)n * K + k] = f2bf(src[i]);
}

// ---------------- generic bf16-MFMA GEMM ----------------
// C[M,Nd] = A[M,K] (+Aadd) @ B[K,Nd]; Bt is bf16 [n][k] row-major.
// 256 thr = 4 waves (2x2), tile 128m x 128n; K mult of 32; Nd <= 128; M mult of 4.
// emode: 0 acc+bias | 1 relu(acc+bias) | 3 (resid+acc*red[2])/anorm[row] | 5 0.5*acc+bias
// outT (optional): bf16 transposed copy outT[col*MP + row] of the f32 result.
__global__ __launch_bounds__(256) void mgemm_kernel(
    const float* __restrict__ A, const float* __restrict__ Aadd, int lda,
    const unsigned short* __restrict__ Bt, int K,
    int emode, float* __restrict__ out, int ldo,
    const float* __restrict__ bias, const float* __restrict__ resid, int ldr,
    const float* __restrict__ anorm, const float* __restrict__ red,
    unsigned short* __restrict__ outT,
    int M, int Nd) {
  __shared__ unsigned short As[128][40];  // [m][k] pad->40 (80B rows, 16B aligned)
  __shared__ unsigned short Bs[128][40];  // [n][k]
  const int tid = threadIdx.x, lane = tid & 63, wave = tid >> 6;
  const int quad = lane >> 4, l16 = lane & 15;
  const int wm = (wave >> 1) * 64, wn = (wave & 1) * 64;
  const int bm = blockIdx.x * 128;
  const int srow = tid >> 1, skh = (tid & 1) * 16;

  f32x4 acc[4][4];
#pragma unroll
  for (int i = 0; i < 4; ++i)
#pragma unroll
    for (int j = 0; j < 4; ++j)
#pragma unroll
      for (int r = 0; r < 4; ++r) acc[i][j][r] = 0.f;

  for (int k0 = 0; k0 < K; k0 += 32) {
    // ---- stage A (f32 -> bf16) ----
    {
      int grow = bm + srow;
      float va[16];
      if (grow < M) {
        const float* ap = A + (size_t)grow * lda + k0 + skh;
        float4 v0 = *(const float4*)(ap + 0), v1 = *(const float4*)(ap + 4);
        float4 v2 = *(const float4*)(ap + 8), v3 = *(const float4*)(ap + 12);
        va[0] = v0.x; va[1] = v0.y; va[2] = v0.z; va[3] = v0.w;
        va[4] = v1.x; va[5] = v1.y; va[6] = v1.z; va[7] = v1.w;
        va[8] = v2.x; va[9] = v2.y; va[10] = v2.z; va[11] = v2.w;
        va[12] = v3.x; va[13] = v3.y; va[14] = v3.z; va[15] = v3.w;
        if (Aadd) {
          const float* ap2 = Aadd + (size_t)grow * lda + k0 + skh;
          float4 w0 = *(const float4*)(ap2 + 0), w1 = *(const float4*)(ap2 + 4);
          float4 w2 = *(const float4*)(ap2 + 8), w3 = *(const float4*)(ap2 + 12);
          va[0] += w0.x; va[1] += w0.y; va[2] += w0.z; va[3] += w0.w;
          va[4] += w1.x; va[5] += w1.y; va[6] += w1.z; va[7] += w1.w;
          va[8] += w2.x; va[9] += w2.y; va[10] += w2.z; va[11] += w2.w;
          va[12] += w3.x; va[13] += w3.y; va[14] += w3.z; va[15] += w3.w;
        }
      } else {
#pragma unroll
        for (int z = 0; z < 16; ++z) va[z] = 0.f;
      }
      bf16x8 p0, p1;
#pragma unroll
      for (int z = 0; z < 8; ++z) { p0[z] = (short)f2bf(va[z]); p1[z] = (short)f2bf(va[z + 8]); }
      *(bf16x8*)&As[srow][skh] = p0;
      *(bf16x8*)&As[srow][skh + 8] = p1;
      // ---- stage B (bf16 copy) ----
      bf16x8 b0, b1;
      if (srow < Nd) {
        const unsigned short* bp = Bt + (size_t)srow * K + k0 + skh;
        b0 = *(const bf16x8*)(bp);
        b1 = *(const bf16x8*)(bp + 8);
      } else {
#pragma unroll
        for (int z = 0; z < 8; ++z) { b0[z] = 0; b1[z] = 0; }
      }
      *(bf16x8*)&Bs[srow][skh] = b0;
      *(bf16x8*)&Bs[srow][skh + 8] = b1;
    }
    __syncthreads();
    bf16x8 af[4], bfr[4];
#pragma unroll
    for (int i = 0; i < 4; ++i) af[i] = *(const bf16x8*)&As[wm + i * 16 + l16][quad * 8];
#pragma unroll
    for (int j = 0; j < 4; ++j) bfr[j] = *(const bf16x8*)&Bs[wn + j * 16 + l16][quad * 8];
#pragma unroll
    for (int i = 0; i < 4; ++i)
#pragma unroll
      for (int j = 0; j < 4; ++j)
        acc[i][j] = __builtin_amdgcn_mfma_f32_16x16x32_bf16(af[i], bfr[j], acc[i][j], 0, 0, 0);
    __syncthreads();
  }

  float s2 = (emode == 3) ? red[2] : 0.f;
#pragma unroll
  for (int j = 0; j < 4; ++j) {
    int col = wn + j * 16 + l16;
    if (col >= Nd) continue;
    float bv = bias ? bias[col] : 0.f;
#pragma unroll
    for (int i = 0; i < 4; ++i) {
      int row0 = bm + wm + i * 16 + quad * 4;
      if (row0 >= M) continue;  // M mult of 4 -> whole group in-bounds
      float o[4];
#pragma unroll
      for (int r = 0; r < 4; ++r) {
        float a = acc[i][j][r];
        int row = row0 + r;
        if (emode == 0) o[r] = a + bv;
        else if (emode == 1) o[r] = fmaxf(a + bv, 0.f);
        else if (emode == 3) o[r] = (resid[(size_t)row * ldr + col] + a * s2) / anorm[row];
        else o[r] = 0.5f * a + bv;
        out[(size_t)row * ldo + col] = o[r];
      }
      if (outT) {
        ushort4 pk;
        pk.x = f2bf(o[0]); pk.y = f2bf(o[1]); pk.z = f2bf(o[2]); pk.w = f2bf(o[3]);
        *(ushort4*)&outT[(size_t)col * MP + row0] = pk;
      }
    }
  }
}

// ---------------- split-K MFMA kT@v ----------------
// part[blk][n*128+m] = sum over this block's nodes of k[node][m]*v[node][n]
__global__ __launch_bounds__(256) void ktv_mfma_kernel(
    const unsigned short* __restrict__ kT, const unsigned short* __restrict__ vT,
    float* __restrict__ part) {
  __shared__ unsigned short As[128][40];
  __shared__ unsigned short Bs[128][40];
  const int tid = threadIdx.x, lane = tid & 63, wave = tid >> 6;
  const int quad = lane >> 4, l16 = lane & 15;
  const int wm = (wave >> 1) * 64, wn = (wave & 1) * 64;
  const int srow = tid >> 1, skh = (tid & 1) * 16;

  f32x4 acc[4][4];
#pragma unroll
  for (int i = 0; i < 4; ++i)
#pragma unroll
    for (int j = 0; j < 4; ++j)
#pragma unroll
      for (int r = 0; r < 4; ++r) acc[i][j][r] = 0.f;

  const int nb0 = blockIdx.x * (CPB * 32);
  for (int c = 0; c < CPB; ++c) {
    int nb = nb0 + c * 32;
    const unsigned short* kp = kT + (size_t)srow * MP + nb + skh;
    *(bf16x8*)&As[srow][skh] = *(const bf16x8*)(kp);
    *(bf16x8*)&As[srow][skh + 8] = *(const bf16x8*)(kp + 8);
    const unsigned short* vp = vT + (size_t)srow * MP + nb + skh;
    *(bf16x8*)&Bs[srow][skh] = *(const bf16x8*)(vp);
    *(bf16x8*)&Bs[srow][skh + 8] = *(const bf16x8*)(vp + 8);
    __syncthreads();
    bf16x8 af[4], bfr[4];
#pragma unroll
    for (int i = 0; i < 4; ++i) af[i] = *(const bf16x8*)&As[wm + i * 16 + l16][quad * 8];
#pragma unroll
    for (int j = 0; j < 4; ++j) bfr[j] = *(const bf16x8*)&Bs[wn + j * 16 + l16][quad * 8];
#pragma unroll
    for (int i = 0; i < 4; ++i)
#pragma unroll
      for (int j = 0; j < 4; ++j)
        acc[i][j] = __builtin_amdgcn_mfma_f32_16x16x32_bf16(af[i], bfr[j], acc[i][j], 0, 0, 0);
    __syncthreads();
  }

  float* pb = part + (size_t)blockIdx.x * 16384;
#pragma unroll
  for (int j = 0; j < 4; ++j) {
    int col = wn + j * 16 + l16;
#pragma unroll
    for (int i = 0; i < 4; ++i) {
      int row0 = wm + i * 16 + quad * 4;
      *(f32x4*)&pb[col * 128 + row0] = acc[i][j];
    }
  }
}

// Btktv[n*128+d] = bf16( sum_s part[s][n*128+d] )  -- directly Bt layout for gr GEMM
__global__ void ktv_reduce_kernel(const float* __restrict__ part,
                                  unsigned short* __restrict__ Btktv) {
  int i = blockIdx.x * blockDim.x + threadIdx.x;
  if (i >= 16384) return;
  float s = 0.f;
  for (int b = 0; b < SKV; ++b) s += part[(size_t)b * 16384 + i];
  Btktv[i] = f2bf(s);
}

// ---------------- env-weighted MFMA GEMM (conv & ctx) ----------------
__global__ __launch_bounds__(256) void mconv_kernel(
    const float* __restrict__ A1, const float* __restrict__ A2,
    const float* __restrict__ env, const unsigned short* __restrict__ Btc, int Kpe,
    int relu_resid, const float* __restrict__ resid, float* __restrict__ out, int M) {
  __shared__ unsigned short As[128][40];
  __shared__ unsigned short Bs[128][40];
  __shared__ float envs[128][4];
  const int tid = threadIdx.x, lane = tid & 63, wave = tid >> 6;
  const int quad = lane >> 4, l16 = lane & 15;
  const int wm = (wave >> 1) * 64, wn = (wave & 1) * 64;
  const int bm = blockIdx.x * 128;
  const int srow = tid >> 1, skh = (tid & 1) * 16;

  for (int i = tid; i < 512; i += 256) {
    int r = i >> 2, c = i & 3;
    int g = bm + r;
    envs[r][c] = (g < M) ? env[(size_t)g * 4 + c] : 0.f;
  }

  f32x4 acc[4][4];
#pragma unroll
  for (int i = 0; i < 4; ++i)
#pragma unroll
    for (int j = 0; j < 4; ++j)
#pragma unroll
      for (int r = 0; r < 4; ++r) acc[i][j][r] = 0.f;

  const int nch = Kpe >> 5;
  for (int e = 0; e < 4; ++e) {
    f32x4 p[4][4];
#pragma unroll
    for (int i = 0; i < 4; ++i)
#pragma unroll
      for (int j = 0; j < 4; ++j)
#pragma unroll
        for (int r = 0; r < 4; ++r) p[i][j][r] = 0.f;

    for (int kc = 0; kc < nch; ++kc) {
      int kof = kc * 32;
      const float* Asrc = A1;
      int ks = kof;
      if (A2 && kof >= 128) { Asrc = A2; ks = kof - 128; }
      {
        int grow = bm + srow;
        float va[16];
        if (grow < M) {
          const float* ap = Asrc + (size_t)grow * 128 + ks + skh;
          float4 v0 = *(const float4*)(ap + 0), v1 = *(const float4*)(ap + 4);
          float4 v2 = *(const float4*)(ap + 8), v3 = *(const float4*)(ap + 12);
          va[0] = v0.x; va[1] = v0.y; va[2] = v0.z; va[3] = v0.w;
          va[4] = v1.x; va[5] = v1.y; va[6] = v1.z; va[7] = v1.w;
          va[8] = v2.x; va[9] = v2.y; va[10] = v2.z; va[11] = v2.w;
          va[12] = v3.x; va[13] = v3.y; va[14] = v3.z; va[15] = v3.w;
        } else {
#pragma unroll
          for (int z = 0; z < 16; ++z) va[z] = 0.f;
        }
        bf16x8 p0, p1;
#pragma unroll
        for (int z = 0; z < 8; ++z) { p0[z] = (short)f2bf(va[z]); p1[z] = (short)f2bf(va[z + 8]); }
        *(bf16x8*)&As[srow][skh] = p0;
        *(bf16x8*)&As[srow][skh + 8] = p1;
        const unsigned short* bp = Btc + ((size_t)e * 128 + srow) * Kpe + kof + skh;
        bf16x8 b0 = *(const bf16x8*)(bp);
        bf16x8 b1 = *(const bf16x8*)(bp + 8);
        *(bf16x8*)&Bs[srow][skh] = b0;
        *(bf16x8*)&Bs[srow][skh + 8] = b1;
      }
      __syncthreads();
      bf16x8 af[4], bfr[4];
#pragma unroll
      for (int i = 0; i < 4; ++i) af[i] = *(const bf16x8*)&As[wm + i * 16 + l16][quad * 8];
#pragma unroll
      for (int j = 0; j < 4; ++j) bfr[j] = *(const bf16x8*)&Bs[wn + j * 16 + l16][quad * 8];
#pragma unroll
      for (int i = 0; i < 4; ++i)
#pragma unroll
        for (int j = 0; j < 4; ++j)
          p[i][j] = __builtin_amdgcn_mfma_f32_16x16x32_bf16(af[i], bfr[j], p[i][j], 0, 0, 0);
      __syncthreads();
    }
#pragma unroll
    for (int i = 0; i < 4; ++i) {
      float ev[4];
#pragma unroll
      for (int r = 0; r < 4; ++r) ev[r] = envs[wm + i * 16 + quad * 4 + r][e];
#pragma unroll
      for (int j = 0; j < 4; ++j)
#pragma unroll
        for (int r = 0; r < 4; ++r) acc[i][j][r] += ev[r] * p[i][j][r];
    }
  }

#pragma unroll
  for (int j = 0; j < 4; ++j) {
    int col = wn + j * 16 + l16;
#pragma unroll
    for (int i = 0; i < 4; ++i) {
#pragma unroll
      for (int r = 0; r < 4; ++r) {
        int row = bm + wm + i * 16 + quad * 4 + r;
        if (row >= M) continue;
        float a = acc[i][j][r];
        float o = relu_resid ? fmaxf(a + resid[(size_t)row * 128 + col], 0.f) : a;
        out[(size_t)row * 128 + col] = o;
      }
    }
  }
}

// ---------------- graph kernels ----------------
__global__ void count_kernel(const int* ei, int* deg, int E) {
  int e = blockIdx.x * blockDim.x + threadIdx.x;
  if (e >= E) return;
  atomicAdd(&deg[ei[E + e]], 1);
}

__global__ __launch_bounds__(256) void scan_kernel(const int* deg, int* start,
                                                   int* cursor, float* inv, int n) {
  __shared__ int part[256];
  int t = threadIdx.x;
  const int Cch = (n + 255) / 256;
  int lo = t * Cch, hi = min(n, lo + Cch);
  int s = 0;
  for (int i = lo; i < hi; ++i) s += deg[i];
  part[t] = s;
  __syncthreads();
  for (int off = 1; off < 256; off <<= 1) {
    int v = part[t];
    int add = (t >= off) ? part[t - off] : 0;
    __syncthreads();
    part[t] = v + add;
    __syncthreads();
  }
  int p = (t == 0) ? 0 : part[t - 1];
  for (int i = lo; i < hi; ++i) {
    start[i] = p; cursor[i] = p;
    int d = deg[i];
    inv[i] = (d > 0) ? rsqrtf((float)d) : 0.f;
    p += d;
  }
  if (t == 255) start[n] = part[255];
}

__global__ void fill_kernel(const int* ei, int* cursor, int* bucket, int E) {
  int e = blockIdx.x * blockDim.x + threadIdx.x;
  if (e >= E) return;
  int r = ei[e], c = ei[E + e];
  int pos = atomicAdd(&cursor[c], 1);
  bucket[pos] = r;
}

__global__ __launch_bounds__(256) void gather_kernel(const float* h, const int* start,
                                                     const int* bucket, const float* inv,
                                                     float* agg, int n) {
  int node = blockIdx.x * 2 + (threadIdx.x >> 7);
  int f = threadIdx.x & 127;
  if (node >= n) return;
  int s0 = start[node], s1 = start[node + 1];
  float acc = 0.f;
  for (int j = s0; j < s1; ++j) {
    int r = bucket[j];
    acc += inv[r] * h[(size_t)r * HH + f];
  }
  agg[(size_t)node * HH + f] = inv[node] * acc;
}

// ---------------- env softmax ----------------
__global__ __launch_bounds__(256) void env_softmax_kernel(const float* __restrict__ h,
                                                          const float* __restrict__ w,
                                                          const float* __restrict__ b,
                                                          float* __restrict__ env, int M) {
  __shared__ float hs[64][129];
  __shared__ float ws[HH * KK];
  int tid = threadIdx.x;
  int base = blockIdx.x * 64;
  for (int i = tid; i < HH * KK; i += 256) ws[i] = w[i];
  {
    int row = tid >> 2, q4 = (tid & 3) * 32;
    int g = base + row;
    if (g < M) {
      const float* hp = h + (size_t)g * HH + q4;
#pragma unroll
      for (int z = 0; z < 8; ++z) {
        float4 v = *(const float4*)(hp + z * 4);
        hs[row][q4 + z * 4 + 0] = v.x; hs[row][q4 + z * 4 + 1] = v.y;
        hs[row][q4 + z * 4 + 2] = v.z; hs[row][q4 + z * 4 + 3] = v.w;
      }
    }
  }
  __syncthreads();
  if (tid < 64 && base + tid < M) {
    float l0 = b[0], l1 = b[1], l2 = b[2], l3 = b[3];
    for (int d = 0; d < HH; ++d) {
      float hv = hs[tid][d];
      l0 += hv * ws[d * 4 + 0]; l1 += hv * ws[d * 4 + 1];
      l2 += hv * ws[d * 4 + 2]; l3 += hv * ws[d * 4 + 3];
    }
    float m = fmaxf(fmaxf(l0, l1), fmaxf(l2, l3));
    float e0 = __expf(l0 - m), e1 = __expf(l1 - m), e2 = __expf(l2 - m), e3 = __expf(l3 - m);
    float s = 1.f / (e0 + e1 + e2 + e3);
    *(float4*)(env + (size_t)(base + tid) * KK) = make_float4(e0 * s, e1 * s, e2 * s, e3 * s);
  }
}

// ---------------- linear-transformer reductions ----------------
__global__ __launch_bounds__(128) void colstats_kernel(const float* q, const float* k,
                                                       float* ksum, float* red, int n) {
  int t = threadIdx.x;
  const int ROWS = 512;
  int lo = blockIdx.x * ROWS, hi = min(n, lo + ROWS);
  float ks = 0.f, sq = 0.f, sk = 0.f;
  for (int r = lo; r < hi; ++r) {
    float kv = k[(size_t)r * HH + t];
    float qv = q[(size_t)r * HH + t];
    ks += kv; sq += qv * qv; sk += kv * kv;
  }
  atomicAdd(&ksum[t], ks);
  __shared__ float sh[2][128];
  sh[0][t] = sq; sh[1][t] = sk;
  __syncthreads();
  for (int off = 64; off > 0; off >>= 1) {
    if (t < off) { sh[0][t] += sh[0][t + off]; sh[1][t] += sh[1][t + off]; }
    __syncthreads();
  }
  if (t == 0) { atomicAdd(&red[0], sh[0][0]); atomicAdd(&red[1], sh[1][0]); }
}

__global__ void scale_kernel(float* red, int n) {
  float nq = fmaxf(sqrtf(red[0]), 1e-12f);
  float nk = fmaxf(sqrtf(red[1]), 1e-12f);
  red[2] = 1.f / (nq * nk * (float)n);
}

__global__ __launch_bounds__(256) void anorm_kernel(const float* q, const float* ksum,
                                                    const float* red, float* anorm, int M) {
  __shared__ float ks[HH];
  for (int i = threadIdx.x; i < HH; i += blockDim.x) ks[i] = ksum[i];
  __syncthreads();
  int n = blockIdx.x * blockDim.x + threadIdx.x;
  if (n >= M) return;
  const float* qp = q + (size_t)n * HH;
  float d = 0.f;
  for (int i = 0; i < HH; ++i) d += qp[i] * ks[i];
  float a = 1.f + d * red[2];
  anorm[n] = fmaxf(a, 1e-12f);
}

// ---------------- host launcher ----------------
extern "C" void kernel_launch(void* const* d_in, const int* in_sizes, int n_in,
                              void* d_out, int out_size, void* d_ws, size_t ws_size,
                              hipStream_t stream) {
  const float* x = (const float*)d_in[0];
  const int* ei = (const int*)d_in[1];
  const float* fc0_w = (const float*)d_in[2];
  const float* fc0_b = (const float*)d_in[3];
  const float* fc1_w = (const float*)d_in[4];
  const float* fc1_b = (const float*)d_in[5];
  const float* env_w = (const float*)d_in[6];
  const float* env_b = (const float*)d_in[7];
  const float* conv_w = (const float*)d_in[8];
  const float* q_w = (const float*)d_in[9];
  const float* q_b = (const float*)d_in[10];
  const float* k_w = (const float*)d_in[11];
  const float* k_b = (const float*)d_in[12];
  const float* v_w = (const float*)d_in[13];
  const float* v_b = (const float*)d_in[14];
  const float* envp_w = (const float*)d_in[15];
  const float* envp_b = (const float*)d_in[16];
  const float* genv_w = (const float*)d_in[17];
  const float* gt_w = (const float*)d_in[18];
  const float* gt_b = (const float*)d_in[19];
  float* out = (float*)d_out;

  const size_t NH = (size_t)NN * HH;
  float* W = (float*)d_ws;
  float* hA = W;             // final h
  float* hB = W + NH;        // layer buffer -> k -> ctx
  float* agg = W + 2 * NH;   // agg -> q
  float* vbuf = W + 3 * NH;  // v -> gh
  float* gr = W + 4 * NH;
  float* env = W + 5 * NH;
  float* genv = env + (size_t)NN * KK;
  float* inv = genv + (size_t)NN * KK;
  float* anorm = inv + NN;
  float* ksum = anorm + NN;
  float* red = ksum + HH;
  int* deg = (int*)(red + 4);
  int* start = deg + NN;
  int* cursor = start + NN + 1;
  int* bucket = cursor + NN;
  unsigned short* wb = (unsigned short*)(((uintptr_t)(bucket + EE) + 15) & ~(uintptr_t)15);
  unsigned short* Btfc0 = wb;                 // 256*128
  unsigned short* Btq = Btfc0 + 32768;        // 128*128
  unsigned short* Btk = Btq + 16384;
  unsigned short* Btv = Btk + 16384;
  unsigned short* Btgt = Btv + 16384;
  unsigned short* Btfc1 = Btgt + 16384;       // 40*128
  unsigned short* Btconv = Btfc1 + 5120;      // 2*4*128*256
  unsigned short* Btgenv = Btconv + 262144;   // 4*128*128
  unsigned short* Btktv = Btgenv + 65536;     // 128*128
  unsigned short* kTbf = Btktv + 16384;       // 128*MP
  unsigned short* vTbf = kTbf + (size_t)HH * MP;
  float* part = (float*)(((uintptr_t)(vTbf + (size_t)HH * MP) + 15) & ~(uintptr_t)15);  // SKV*16384

  float* q = agg;
  float* kb = hB;
  float* ctx = hB;
  float* gh = vbuf;

  dim3 b256(256);
  const int MB = (NN + 127) / 128;  // 391

  zero_i32_kernel<<<dim3((NN + 255) / 256), b256, 0, stream>>>(deg, NN);
  zero_f32_kernel<<<dim3(1), dim3(HH + 4), 0, stream>>>(ksum, HH + 4);
  padzero_kernel<<<dim3((HH * (MP - NN) + 255) / 256), b256, 0, stream>>>(kTbf, vTbf);

  // CSR build
  count_kernel<<<dim3((EE + 255) / 256), b256, 0, stream>>>(ei, deg, EE);
  scan_kernel<<<dim3(1), b256, 0, stream>>>(deg, start, cursor, inv, NN);
  fill_kernel<<<dim3((EE + 255) / 256), b256, 0, stream>>>(ei, cursor, bucket, EE);

  // weight prep: transpose+bf16
  tcvt_kernel<<<dim3((32768 + 255) / 256), b256, 0, stream>>>(fc0_w, Btfc0, 256, 128, 1);
  tcvt_kernel<<<dim3((16384 + 255) / 256), b256, 0, stream>>>(q_w, Btq, 128, 128, 1);
  tcvt_kernel<<<dim3((16384 + 255) / 256), b256, 0, stream>>>(k_w, Btk, 128, 128, 1);
  tcvt_kernel<<<dim3((16384 + 255) / 256), b256, 0, stream>>>(v_w, Btv, 128, 128, 1);
  tcvt_kernel<<<dim3((16384 + 255) / 256), b256, 0, stream>>>(gt_w, Btgt, 128, 128, 1);
  tcvt_kernel<<<dim3((5120 + 255) / 256), b256, 0, stream>>>(fc1_w, Btfc1, 128, 40, 1);
  tcvt_kernel<<<dim3((262144 + 255) / 256), b256, 0, stream>>>(conv_w, Btconv, 256, 128, 8);
  tcvt_kernel<<<dim3((65536 + 255) / 256), b256, 0, stream>>>(genv_w, Btgenv, 128, 128, 4);

  // fc0: h = relu(x @ fc0_w + b)
  mgemm_kernel<<<dim3(MB), b256, 0, stream>>>(
      x, nullptr, DD, Btfc0, 256, 1, hA, HH, fc0_b, nullptr, 0, nullptr, nullptr,
      nullptr, NN, HH);

  // conv layers
  float* hcur = hA;
  float* hnext = hB;
  for (int l = 0; l < 2; ++l) {
    env_softmax_kernel<<<dim3((NN + 63) / 64), b256, 0, stream>>>(
        hcur, env_w + (size_t)l * HH * KK, env_b + (size_t)l * KK, env, NN);
    gather_kernel<<<dim3((NN + 1) / 2), b256, 0, stream>>>(hcur, start, bucket, inv, agg, NN);
    mconv_kernel<<<dim3(MB), b256, 0, stream>>>(
        agg, hcur, env, Btconv + (size_t)l * 131072, 256, 1, hcur, hnext, NN);
    float* t = hcur; hcur = hnext; hnext = t;
  }
  // hcur == hA

  // q, k, v (k and v also emit transposed bf16 copies for the ktv MFMA)
  mgemm_kernel<<<dim3(MB), b256, 0, stream>>>(
      hcur, nullptr, HH, Btq, 128, 0, q, HH, q_b, nullptr, 0, nullptr, nullptr,
      nullptr, NN, HH);
  mgemm_kernel<<<dim3(MB), b256, 0, stream>>>(
      hcur, nullptr, HH, Btk, 128, 0, kb, HH, k_b, nullptr, 0, nullptr, nullptr,
      kTbf, NN, HH);
  mgemm_kernel<<<dim3(MB), b256, 0, stream>>>(
      hcur, nullptr, HH, Btv, 128, 0, vbuf, HH, v_b, nullptr, 0, nullptr, nullptr,
      vTbf, NN, HH);

  colstats_kernel<<<dim3((NN + 511) / 512), dim3(128), 0, stream>>>(q, kb, ksum, red, NN);
  ktv_mfma_kernel<<<dim3(SKV), b256, 0, stream>>>(kTbf, vTbf, part);
  ktv_reduce_kernel<<<dim3(64), b256, 0, stream>>>(part, Btktv);
  scale_kernel<<<dim3(1), dim3(1), 0, stream>>>(red, NN);
  anorm_kernel<<<dim3((NN + 255) / 256), b256, 0, stream>>>(q, ksum, red, anorm, NN);

  // gr = (v + q @ ktv * red[2]) / anorm
  mgemm_kernel<<<dim3(MB), b256, 0, stream>>>(
      q, nullptr, HH, Btktv, 128, 3, gr, HH, nullptr, vbuf, HH, anorm, red,
      nullptr, NN, HH);

  // genv = softmax(gr @ envp_w + envp_b)
  env_softmax_kernel<<<dim3((NN + 63) / 64), b256, 0, stream>>>(gr, envp_w, envp_b, genv, NN);

  // ctx = sum_k genv[:,k] * (gr @ genv_w[k])
  mconv_kernel<<<dim3(MB), b256, 0, stream>>>(
      gr, nullptr, genv, Btgenv, 128, 0, nullptr, ctx, NN);

  // gh = relu(ctx @ gt_w + gt_b)
  mgemm_kernel<<<dim3(MB), b256, 0, stream>>>(
      ctx, nullptr, HH, Btgt, 128, 1, gh, HH, gt_b, nullptr, 0, nullptr, nullptr,
      nullptr, NN, HH);

  // out = 0.5*((h+gh) @ fc1_w) + fc1_b
  mgemm_kernel<<<dim3(MB), b256, 0, stream>>>(
      hcur, gh, HH, Btfc1, 128, 5, out, CC, fc1_b, nullptr, 0, nullptr, nullptr,
      nullptr, NN, CC);
}

// Round 8
// 1048.352 us; speedup vs baseline: 1.7529x; 1.1969x over previous
//
#include <hip/hip_runtime.h>

#define DEV __device__ __forceinline__

static constexpr int NN = 50000;   // nodes
static constexpr int DD = 256;     // input dim
static constexpr int HH = 128;     // hidden
static constexpr int CC = 40;      // classes
static constexpr int KK = 4;       // envs
static constexpr int EE = 800000;  // edges
static constexpr int MP = 50176;   // padded node count (196*256, mult of 32)
static constexpr int SKV = 196;    // split-K blocks for ktv
static constexpr int CPB = 8;      // 32-node chunks per ktv block
static constexpr int CSB = 391;    // colstats blocks (ceil(NN/128))

typedef __attribute__((ext_vector_type(8))) short bf16x8;
typedef __attribute__((ext_vector_type(4))) float f32x4;

DEV unsigned short f2bf(float f) {
  union { float f; unsigned int i; } c; c.f = f;
  unsigned int x = c.i;
  x += 0x7FFFu + ((x >> 16) & 1u);   // round-to-nearest-even
  return (unsigned short)(x >> 16);
}
DEV float bfbits2f(unsigned int hi16bits) {  // takes value already in high-16 position
  union { unsigned int i; float f; } c; c.i = hi16bits; return c.f;
}

// harness-named kernel (unused in pipeline)
__global__ void MLEI_12970801234193_kernel(float* out, int n) {
  int i = blockIdx.x * blockDim.x + threadIdx.x;
  if (i < n) out[i] = 7.0f;
}

__global__ void zero_i32_kernel(int* p, int n) {
  int i = blockIdx.x * blockDim.x + threadIdx.x;
  if (i < n) p[i] = 0;
}

// zero the pad columns [NN, MP) of the transposed bf16 k/v buffers
__global__ void padzero_kernel(unsigned short* kT, unsigned short* vT) {
  int i = blockIdx.x * blockDim.x + threadIdx.x;
  const int PW = MP - NN;  // 176
  if (i >= HH * PW) return;
  int f = i / PW, c = i - f * PW;
  kT[(size_t)f * MP + NN + c] = 0;
  vT[(size_t)f * MP + NN + c] = 0;
}

// transpose-convert: dst[m][n][k] = bf16(src[m][k][n]); nm matrices of K x N
__global__ void tcvt_kernel(const float* __restrict__ src, unsigned short* __restrict__ dst,
                            int K, int N, int nm) {
  int i = blockIdx.x * blockDim.x + threadIdx.x;
  int tot = nm * K * N;
  if (i >= tot) return;
  int m = i / (K * N);
  int rem = i - m * K * N;
  int k = rem / N;
  int n = rem - k * N;
  dst[(size_t)m * K * N + (size_t)n * K + k] = f2bf(src[i]);
}

// ---------------- generic bf16-MFMA GEMM ----------------
// C[M,Nd] = A[M,K] (+Aadd) @ B[K,Nd]; Bt is bf16 [n][k] row-major.
// emode: 0 acc+bias | 1 relu(acc+bias) | 3 (resid+acc*red[2])/anorm[row] | 5 0.5*acc+bias
// outT: optional bf16 transposed copy outT[col*MP + row].
// outBf: optional bf16 row-major copy outBf[row*128+col] scaled by rowscale[row].
__global__ __launch_bounds__(256) void mgemm_kernel(
    const float* __restrict__ A, const float* __restrict__ Aadd, int lda,
    const unsigned short* __restrict__ Bt, int K,
    int emode, float* __restrict__ out, int ldo,
    const float* __restrict__ bias, const float* __restrict__ resid, int ldr,
    const float* __restrict__ anorm, const float* __restrict__ red,
    unsigned short* __restrict__ outT,
    unsigned short* __restrict__ outBf, const float* __restrict__ rowscale,
    int M, int Nd) {
  __shared__ unsigned short As[128][40];
  __shared__ unsigned short Bs[128][40];
  const int tid = threadIdx.x, lane = tid & 63, wave = tid >> 6;
  const int quad = lane >> 4, l16 = lane & 15;
  const int wm = (wave >> 1) * 64, wn = (wave & 1) * 64;
  const int bm = blockIdx.x * 128;
  const int srow = tid >> 1, skh = (tid & 1) * 16;

  f32x4 acc[4][4];
#pragma unroll
  for (int i = 0; i < 4; ++i)
#pragma unroll
    for (int j = 0; j < 4; ++j)
#pragma unroll
      for (int r = 0; r < 4; ++r) acc[i][j][r] = 0.f;

  for (int k0 = 0; k0 < K; k0 += 32) {
    {
      int grow = bm + srow;
      float va[16];
      if (grow < M) {
        const float* ap = A + (size_t)grow * lda + k0 + skh;
        float4 v0 = *(const float4*)(ap + 0), v1 = *(const float4*)(ap + 4);
        float4 v2 = *(const float4*)(ap + 8), v3 = *(const float4*)(ap + 12);
        va[0] = v0.x; va[1] = v0.y; va[2] = v0.z; va[3] = v0.w;
        va[4] = v1.x; va[5] = v1.y; va[6] = v1.z; va[7] = v1.w;
        va[8] = v2.x; va[9] = v2.y; va[10] = v2.z; va[11] = v2.w;
        va[12] = v3.x; va[13] = v3.y; va[14] = v3.z; va[15] = v3.w;
        if (Aadd) {
          const float* ap2 = Aadd + (size_t)grow * lda + k0 + skh;
          float4 w0 = *(const float4*)(ap2 + 0), w1 = *(const float4*)(ap2 + 4);
          float4 w2 = *(const float4*)(ap2 + 8), w3 = *(const float4*)(ap2 + 12);
          va[0] += w0.x; va[1] += w0.y; va[2] += w0.z; va[3] += w0.w;
          va[4] += w1.x; va[5] += w1.y; va[6] += w1.z; va[7] += w1.w;
          va[8] += w2.x; va[9] += w2.y; va[10] += w2.z; va[11] += w2.w;
          va[12] += w3.x; va[13] += w3.y; va[14] += w3.z; va[15] += w3.w;
        }
      } else {
#pragma unroll
        for (int z = 0; z < 16; ++z) va[z] = 0.f;
      }
      bf16x8 p0, p1;
#pragma unroll
      for (int z = 0; z < 8; ++z) { p0[z] = (short)f2bf(va[z]); p1[z] = (short)f2bf(va[z + 8]); }
      *(bf16x8*)&As[srow][skh] = p0;
      *(bf16x8*)&As[srow][skh + 8] = p1;
      bf16x8 b0, b1;
      if (srow < Nd) {
        const unsigned short* bp = Bt + (size_t)srow * K + k0 + skh;
        b0 = *(const bf16x8*)(bp);
        b1 = *(const bf16x8*)(bp + 8);
      } else {
#pragma unroll
        for (int z = 0; z < 8; ++z) { b0[z] = 0; b1[z] = 0; }
      }
      *(bf16x8*)&Bs[srow][skh] = b0;
      *(bf16x8*)&Bs[srow][skh + 8] = b1;
    }
    __syncthreads();
    bf16x8 af[4], bfr[4];
#pragma unroll
    for (int i = 0; i < 4; ++i) af[i] = *(const bf16x8*)&As[wm + i * 16 + l16][quad * 8];
#pragma unroll
    for (int j = 0; j < 4; ++j) bfr[j] = *(const bf16x8*)&Bs[wn + j * 16 + l16][quad * 8];
#pragma unroll
    for (int i = 0; i < 4; ++i)
#pragma unroll
      for (int j = 0; j < 4; ++j)
        acc[i][j] = __builtin_amdgcn_mfma_f32_16x16x32_bf16(af[i], bfr[j], acc[i][j], 0, 0, 0);
    __syncthreads();
  }

  float s2 = (emode == 3) ? red[2] : 0.f;
#pragma unroll
  for (int j = 0; j < 4; ++j) {
    int col = wn + j * 16 + l16;
    if (col >= Nd) continue;
    float bv = bias ? bias[col] : 0.f;
#pragma unroll
    for (int i = 0; i < 4; ++i) {
      int row0 = bm + wm + i * 16 + quad * 4;
      if (row0 >= M) continue;  // M mult of 4 -> whole group in-bounds
      float o[4];
#pragma unroll
      for (int r = 0; r < 4; ++r) {
        float a = acc[i][j][r];
        int row = row0 + r;
        if (emode == 0) o[r] = a + bv;
        else if (emode == 1) o[r] = fmaxf(a + bv, 0.f);
        else if (emode == 3) o[r] = (resid[(size_t)row * ldr + col] + a * s2) / anorm[row];
        else o[r] = 0.5f * a + bv;
        out[(size_t)row * ldo + col] = o[r];
      }
      if (outT) {
        ushort4 pk;
        pk.x = f2bf(o[0]); pk.y = f2bf(o[1]); pk.z = f2bf(o[2]); pk.w = f2bf(o[3]);
        *(ushort4*)&outT[(size_t)col * MP + row0] = pk;
      }
      if (outBf) {
#pragma unroll
        for (int r = 0; r < 4; ++r) {
          float rs = rowscale ? rowscale[row0 + r] : 1.f;
          outBf[(size_t)(row0 + r) * 128 + col] = f2bf(o[r] * rs);
        }
      }
    }
  }
}

// ---------------- split-K MFMA kT@v ----------------
__global__ __launch_bounds__(256) void ktv_mfma_kernel(
    const unsigned short* __restrict__ kT, const unsigned short* __restrict__ vT,
    float* __restrict__ part) {
  __shared__ unsigned short As[128][40];
  __shared__ unsigned short Bs[128][40];
  const int tid = threadIdx.x, lane = tid & 63, wave = tid >> 6;
  const int quad = lane >> 4, l16 = lane & 15;
  const int wm = (wave >> 1) * 64, wn = (wave & 1) * 64;
  const int srow = tid >> 1, skh = (tid & 1) * 16;

  f32x4 acc[4][4];
#pragma unroll
  for (int i = 0; i < 4; ++i)
#pragma unroll
    for (int j = 0; j < 4; ++j)
#pragma unroll
      for (int r = 0; r < 4; ++r) acc[i][j][r] = 0.f;

  const int nb0 = blockIdx.x * (CPB * 32);
  for (int c = 0; c < CPB; ++c) {
    int nb = nb0 + c * 32;
    const unsigned short* kp = kT + (size_t)srow * MP + nb + skh;
    *(bf16x8*)&As[srow][skh] = *(const bf16x8*)(kp);
    *(bf16x8*)&As[srow][skh + 8] = *(const bf16x8*)(kp + 8);
    const unsigned short* vp = vT + (size_t)srow * MP + nb + skh;
    *(bf16x8*)&Bs[srow][skh] = *(const bf16x8*)(vp);
    *(bf16x8*)&Bs[srow][skh + 8] = *(const bf16x8*)(vp + 8);
    __syncthreads();
    bf16x8 af[4], bfr[4];
#pragma unroll
    for (int i = 0; i < 4; ++i) af[i] = *(const bf16x8*)&As[wm + i * 16 + l16][quad * 8];
#pragma unroll
    for (int j = 0; j < 4; ++j) bfr[j] = *(const bf16x8*)&Bs[wn + j * 16 + l16][quad * 8];
#pragma unroll
    for (int i = 0; i < 4; ++i)
#pragma unroll
      for (int j = 0; j < 4; ++j)
        acc[i][j] = __builtin_amdgcn_mfma_f32_16x16x32_bf16(af[i], bfr[j], acc[i][j], 0, 0, 0);
    __syncthreads();
  }

  float* pb = part + (size_t)blockIdx.x * 16384;
#pragma unroll
  for (int j = 0; j < 4; ++j) {
    int col = wn + j * 16 + l16;
#pragma unroll
    for (int i = 0; i < 4; ++i) {
      int row0 = wm + i * 16 + quad * 4;
      *(f32x4*)&pb[col * 128 + row0] = acc[i][j];
    }
  }
}

__global__ void ktv_reduce_kernel(const float* __restrict__ part,
                                  unsigned short* __restrict__ Btktv) {
  int i = blockIdx.x * blockDim.x + threadIdx.x;
  if (i >= 16384) return;
  float s = 0.f;
  for (int b = 0; b < SKV; ++b) s += part[(size_t)b * 16384 + i];
  Btktv[i] = f2bf(s);
}

// ---------------- env-weighted MFMA GEMM (conv & ctx) ----------------
__global__ __launch_bounds__(256) void mconv_kernel(
    const float* __restrict__ A1, const float* __restrict__ A2,
    const float* __restrict__ env, const unsigned short* __restrict__ Btc, int Kpe,
    int relu_resid, const float* __restrict__ resid, float* __restrict__ out,
    unsigned short* __restrict__ outBf, const float* __restrict__ rowscale, int M) {
  __shared__ unsigned short As[128][40];
  __shared__ unsigned short Bs[128][40];
  __shared__ float envs[128][4];
  const int tid = threadIdx.x, lane = tid & 63, wave = tid >> 6;
  const int quad = lane >> 4, l16 = lane & 15;
  const int wm = (wave >> 1) * 64, wn = (wave & 1) * 64;
  const int bm = blockIdx.x * 128;
  const int srow = tid >> 1, skh = (tid & 1) * 16;

  for (int i = tid; i < 512; i += 256) {
    int r = i >> 2, c = i & 3;
    int g = bm + r;
    envs[r][c] = (g < M) ? env[(size_t)g * 4 + c] : 0.f;
  }

  f32x4 acc[4][4];
#pragma unroll
  for (int i = 0; i < 4; ++i)
#pragma unroll
    for (int j = 0; j < 4; ++j)
#pragma unroll
      for (int r = 0; r < 4; ++r) acc[i][j][r] = 0.f;

  const int nch = Kpe >> 5;
  for (int e = 0; e < 4; ++e) {
    f32x4 p[4][4];
#pragma unroll
    for (int i = 0; i < 4; ++i)
#pragma unroll
      for (int j = 0; j < 4; ++j)
#pragma unroll
        for (int r = 0; r < 4; ++r) p[i][j][r] = 0.f;

    for (int kc = 0; kc < nch; ++kc) {
      int kof = kc * 32;
      const float* Asrc = A1;
      int ks = kof;
      if (A2 && kof >= 128) { Asrc = A2; ks = kof - 128; }
      {
        int grow = bm + srow;
        float va[16];
        if (grow < M) {
          const float* ap = Asrc + (size_t)grow * 128 + ks + skh;
          float4 v0 = *(const float4*)(ap + 0), v1 = *(const float4*)(ap + 4);
          float4 v2 = *(const float4*)(ap + 8), v3 = *(const float4*)(ap + 12);
          va[0] = v0.x; va[1] = v0.y; va[2] = v0.z; va[3] = v0.w;
          va[4] = v1.x; va[5] = v1.y; va[6] = v1.z; va[7] = v1.w;
          va[8] = v2.x; va[9] = v2.y; va[10] = v2.z; va[11] = v2.w;
          va[12] = v3.x; va[13] = v3.y; va[14] = v3.z; va[15] = v3.w;
        } else {
#pragma unroll
          for (int z = 0; z < 16; ++z) va[z] = 0.f;
        }
        bf16x8 p0, p1;
#pragma unroll
        for (int z = 0; z < 8; ++z) { p0[z] = (short)f2bf(va[z]); p1[z] = (short)f2bf(va[z + 8]); }
        *(bf16x8*)&As[srow][skh] = p0;
        *(bf16x8*)&As[srow][skh + 8] = p1;
        const unsigned short* bp = Btc + ((size_t)e * 128 + srow) * Kpe + kof + skh;
        bf16x8 b0 = *(const bf16x8*)(bp);
        bf16x8 b1 = *(const bf16x8*)(bp + 8);
        *(bf16x8*)&Bs[srow][skh] = b0;
        *(bf16x8*)&Bs[srow][skh + 8] = b1;
      }
      __syncthreads();
      bf16x8 af[4], bfr[4];
#pragma unroll
      for (int i = 0; i < 4; ++i) af[i] = *(const bf16x8*)&As[wm + i * 16 + l16][quad * 8];
#pragma unroll
      for (int j = 0; j < 4; ++j) bfr[j] = *(const bf16x8*)&Bs[wn + j * 16 + l16][quad * 8];
#pragma unroll
      for (int i = 0; i < 4; ++i)
#pragma unroll
        for (int j = 0; j < 4; ++j)
          p[i][j] = __builtin_amdgcn_mfma_f32_16x16x32_bf16(af[i], bfr[j], p[i][j], 0, 0, 0);
      __syncthreads();
    }
#pragma unroll
    for (int i = 0; i < 4; ++i) {
      float ev[4];
#pragma unroll
      for (int r = 0; r < 4; ++r) ev[r] = envs[wm + i * 16 + quad * 4 + r][e];
#pragma unroll
      for (int j = 0; j < 4; ++j)
#pragma unroll
        for (int r = 0; r < 4; ++r) acc[i][j][r] += ev[r] * p[i][j][r];
    }
  }

#pragma unroll
  for (int j = 0; j < 4; ++j) {
    int col = wn + j * 16 + l16;
#pragma unroll
    for (int i = 0; i < 4; ++i) {
      int row0 = bm + wm + i * 16 + quad * 4;
      if (row0 >= M) continue;
#pragma unroll
      for (int r = 0; r < 4; ++r) {
        int row = row0 + r;
        float a = acc[i][j][r];
        float o = relu_resid ? fmaxf(a + resid[(size_t)row * 128 + col], 0.f) : a;
        out[(size_t)row * 128 + col] = o;
        if (outBf) {
          float rs = rowscale ? rowscale[row] : 1.f;
          outBf[(size_t)row * 128 + col] = f2bf(o * rs);
        }
      }
    }
  }
}

// ---------------- graph kernels ----------------
__global__ void count_kernel(const int* ei, int* deg, int E) {
  int e = blockIdx.x * blockDim.x + threadIdx.x;
  if (e >= E) return;
  atomicAdd(&deg[ei[E + e]], 1);
}

__global__ __launch_bounds__(256) void scan_kernel(const int* deg, int* start,
                                                   int* cursor, float* inv, int n) {
  __shared__ int part[256];
  int t = threadIdx.x;
  const int Cch = (n + 255) / 256;
  int lo = t * Cch, hi = min(n, lo + Cch);
  int s = 0;
  for (int i = lo; i < hi; ++i) s += deg[i];
  part[t] = s;
  __syncthreads();
  for (int off = 1; off < 256; off <<= 1) {
    int v = part[t];
    int add = (t >= off) ? part[t - off] : 0;
    __syncthreads();
    part[t] = v + add;
    __syncthreads();
  }
  int p = (t == 0) ? 0 : part[t - 1];
  for (int i = lo; i < hi; ++i) {
    start[i] = p; cursor[i] = p;
    int d = deg[i];
    inv[i] = (d > 0) ? rsqrtf((float)d) : 0.f;
    p += d;
  }
  if (t == 255) start[n] = part[255];
}

__global__ void fill_kernel(const int* ei, int* cursor, int* bucket, int E) {
  int e = blockIdx.x * blockDim.x + threadIdx.x;
  if (e >= E) return;
  int r = ei[e], c = ei[E + e];
  int pos = atomicAdd(&cursor[c], 1);
  bucket[pos] = r;
}

// gather from pre-scaled bf16 h: agg[n,f] = inv[n] * sum_edges hs[src][f]
// 4 nodes/block, one 64-lane wave per node, 2 features per lane via uint load.
__global__ __launch_bounds__(256) void gather_kernel(
    const unsigned short* __restrict__ hs, const int* __restrict__ start,
    const int* __restrict__ bucket, const float* __restrict__ inv,
    float* __restrict__ agg, int n) {
  int node = blockIdx.x * 4 + (threadIdx.x >> 6);
  if (node >= n) return;
  int f2 = (threadIdx.x & 63) * 2;
  int s0 = start[node], s1 = start[node + 1];
  float a0 = 0.f, a1 = 0.f;
  for (int j = s0; j < s1; ++j) {
    int r = bucket[j];
    unsigned int u = *(const unsigned int*)&hs[(size_t)r * 128 + f2];
    a0 += bfbits2f(u << 16);
    a1 += bfbits2f(u & 0xFFFF0000u);
  }
  float iv = inv[node];
  *(float2*)&agg[(size_t)node * 128 + f2] = make_float2(iv * a0, iv * a1);
}

// ---------------- env softmax ----------------
__global__ __launch_bounds__(256) void env_softmax_kernel(const float* __restrict__ h,
                                                          const float* __restrict__ w,
                                                          const float* __restrict__ b,
                                                          float* __restrict__ env, int M) {
  __shared__ float hsd[64][129];
  __shared__ float ws[HH * KK];
  int tid = threadIdx.x;
  int base = blockIdx.x * 64;
  for (int i = tid; i < HH * KK; i += 256) ws[i] = w[i];
  {
    int row = tid >> 2, q4 = (tid & 3) * 32;
    int g = base + row;
    if (g < M) {
      const float* hp = h + (size_t)g * HH + q4;
#pragma unroll
      for (int z = 0; z < 8; ++z) {
        float4 v = *(const float4*)(hp + z * 4);
        hsd[row][q4 + z * 4 + 0] = v.x; hsd[row][q4 + z * 4 + 1] = v.y;
        hsd[row][q4 + z * 4 + 2] = v.z; hsd[row][q4 + z * 4 + 3] = v.w;
      }
    }
  }
  __syncthreads();
  if (tid < 64 && base + tid < M) {
    float l0 = b[0], l1 = b[1], l2 = b[2], l3 = b[3];
    for (int d = 0; d < HH; ++d) {
      float hv = hsd[tid][d];
      l0 += hv * ws[d * 4 + 0]; l1 += hv * ws[d * 4 + 1];
      l2 += hv * ws[d * 4 + 2]; l3 += hv * ws[d * 4 + 3];
    }
    float m = fmaxf(fmaxf(l0, l1), fmaxf(l2, l3));
    float e0 = __expf(l0 - m), e1 = __expf(l1 - m), e2 = __expf(l2 - m), e3 = __expf(l3 - m);
    float s = 1.f / (e0 + e1 + e2 + e3);
    *(float4*)(env + (size_t)(base + tid) * KK) = make_float4(e0 * s, e1 * s, e2 * s, e3 * s);
  }
}

// ---------------- linear-transformer reductions: two-stage colstats ----------------
// stage 1: 128-row slabs -> partK[blk][128] (colsum of k), partS[blk][2] (sumsq q, k)
__global__ __launch_bounds__(256) void colstats1_kernel(
    const float* __restrict__ q, const float* __restrict__ k,
    float* __restrict__ partK, float* __restrict__ partS, int n) {
  int tid = threadIdx.x, ty = tid >> 7, tx = tid & 127;
  int lo = blockIdx.x * 128 + ty, hi = min(n, blockIdx.x * 128 + 128);
  float ks = 0.f, sq = 0.f, sk = 0.f;
  for (int r = lo; r < hi; r += 2) {
    float kv = k[(size_t)r * HH + tx];
    float qv = q[(size_t)r * HH + tx];
    ks += kv; sq += qv * qv; sk += kv * kv;
  }
  __shared__ float sks[2][128];
  __shared__ float ssq[256], ssk[256];
  sks[ty][tx] = ks; ssq[tid] = sq; ssk[tid] = sk;
  __syncthreads();
  if (ty == 0) partK[(size_t)blockIdx.x * 128 + tx] = sks[0][tx] + sks[1][tx];
  for (int off = 128; off > 0; off >>= 1) {
    if (tid < off) { ssq[tid] += ssq[tid + off]; ssk[tid] += ssk[tid + off]; }
    __syncthreads();
  }
  if (tid == 0) { partS[blockIdx.x * 2] = ssq[0]; partS[blockIdx.x * 2 + 1] = ssk[0]; }
}

// stage 2: reduce partials -> ksum[128], red[0], red[1]
__global__ __launch_bounds__(256) void colstats2_kernel(
    const float* __restrict__ partK, const float* __restrict__ partS,
    float* __restrict__ ksum, float* __restrict__ red) {
  int t = threadIdx.x;
  if (t < 128) {
    float s = 0.f;
    for (int b = 0; b < CSB; ++b) s += partK[(size_t)b * 128 + t];
    ksum[t] = s;
  } else if (t == 128 || t == 129) {
    float s = 0.f;
    for (int b = 0; b < CSB; ++b) s += partS[b * 2 + (t - 128)];
    red[t - 128] = s;
  }
}

__global__ void scale_kernel(float* red, int n) {
  float nq = fmaxf(sqrtf(red[0]), 1e-12f);
  float nk = fmaxf(sqrtf(red[1]), 1e-12f);
  red[2] = 1.f / (nq * nk * (float)n);
}

__global__ __launch_bounds__(256) void anorm_kernel(const float* q, const float* ksum,
                                                    const float* red, float* anorm, int M) {
  __shared__ float ks[HH];
  for (int i = threadIdx.x; i < HH; i += blockDim.x) ks[i] = ksum[i];
  __syncthreads();
  int n = blockIdx.x * blockDim.x + threadIdx.x;
  if (n >= M) return;
  const float* qp = q + (size_t)n * HH;
  float d = 0.f;
  for (int i = 0; i < HH; ++i) d += qp[i] * ks[i];
  float a = 1.f + d * red[2];
  anorm[n] = fmaxf(a, 1e-12f);
}

// ---------------- host launcher ----------------
extern "C" void kernel_launch(void* const* d_in, const int* in_sizes, int n_in,
                              void* d_out, int out_size, void* d_ws, size_t ws_size,
                              hipStream_t stream) {
  const float* x = (const float*)d_in[0];
  const int* ei = (const int*)d_in[1];
  const float* fc0_w = (const float*)d_in[2];
  const float* fc0_b = (const float*)d_in[3];
  const float* fc1_w = (const float*)d_in[4];
  const float* fc1_b = (const float*)d_in[5];
  const float* env_w = (const float*)d_in[6];
  const float* env_b = (const float*)d_in[7];
  const float* conv_w = (const float*)d_in[8];
  const float* q_w = (const float*)d_in[9];
  const float* q_b = (const float*)d_in[10];
  const float* k_w = (const float*)d_in[11];
  const float* k_b = (const float*)d_in[12];
  const float* v_w = (const float*)d_in[13];
  const float* v_b = (const float*)d_in[14];
  const float* envp_w = (const float*)d_in[15];
  const float* envp_b = (const float*)d_in[16];
  const float* genv_w = (const float*)d_in[17];
  const float* gt_w = (const float*)d_in[18];
  const float* gt_b = (const float*)d_in[19];
  float* out = (float*)d_out;

  const size_t NH = (size_t)NN * HH;
  float* W = (float*)d_ws;
  float* hA = W;             // final h
  float* hB = W + NH;        // layer buffer -> k -> ctx
  float* agg = W + 2 * NH;   // agg -> q
  float* vbuf = W + 3 * NH;  // v -> gh
  float* gr = W + 4 * NH;
  float* env = W + 5 * NH;
  float* genv = env + (size_t)NN * KK;
  float* inv = genv + (size_t)NN * KK;
  float* anorm = inv + NN;
  float* ksum = anorm + NN;
  float* red = ksum + HH;
  int* deg = (int*)(red + 4);
  int* start = deg + NN;
  int* cursor = start + NN + 1;
  int* bucket = cursor + NN;
  unsigned short* wb = (unsigned short*)(((uintptr_t)(bucket + EE) + 15) & ~(uintptr_t)15);
  unsigned short* Btfc0 = wb;                 // 256*128
  unsigned short* Btq = Btfc0 + 32768;
  unsigned short* Btk = Btq + 16384;
  unsigned short* Btv = Btk + 16384;
  unsigned short* Btgt = Btv + 16384;
  unsigned short* Btfc1 = Btgt + 16384;       // 40*128
  unsigned short* Btconv = Btfc1 + 5120;      // 2*4*128*256
  unsigned short* Btgenv = Btconv + 262144;   // 4*128*128
  unsigned short* Btktv = Btgenv + 65536;     // 128*128
  unsigned short* kTbf = Btktv + 16384;       // 128*MP
  unsigned short* vTbf = kTbf + (size_t)HH * MP;
  unsigned short* hsb = vTbf + (size_t)HH * MP;  // NN*128 bf16 (scaled h)
  float* part = (float*)(((uintptr_t)(hsb + NH) + 15) & ~(uintptr_t)15);  // SKV*16384
  float* partK = part + (size_t)SKV * 16384;  // CSB*128
  float* partS = partK + (size_t)CSB * 128;   // CSB*2

  float* q = agg;
  float* kb = hB;
  float* ctx = hB;
  float* gh = vbuf;

  dim3 b256(256);
  const int MB = (NN + 127) / 128;  // 391

  zero_i32_kernel<<<dim3((NN + 255) / 256), b256, 0, stream>>>(deg, NN);
  padzero_kernel<<<dim3((HH * (MP - NN) + 255) / 256), b256, 0, stream>>>(kTbf, vTbf);

  // CSR build
  count_kernel<<<dim3((EE + 255) / 256), b256, 0, stream>>>(ei, deg, EE);
  scan_kernel<<<dim3(1), b256, 0, stream>>>(deg, start, cursor, inv, NN);
  fill_kernel<<<dim3((EE + 255) / 256), b256, 0, stream>>>(ei, cursor, bucket, EE);

  // weight prep
  tcvt_kernel<<<dim3((32768 + 255) / 256), b256, 0, stream>>>(fc0_w, Btfc0, 256, 128, 1);
  tcvt_kernel<<<dim3((16384 + 255) / 256), b256, 0, stream>>>(q_w, Btq, 128, 128, 1);
  tcvt_kernel<<<dim3((16384 + 255) / 256), b256, 0, stream>>>(k_w, Btk, 128, 128, 1);
  tcvt_kernel<<<dim3((16384 + 255) / 256), b256, 0, stream>>>(v_w, Btv, 128, 128, 1);
  tcvt_kernel<<<dim3((16384 + 255) / 256), b256, 0, stream>>>(gt_w, Btgt, 128, 128, 1);
  tcvt_kernel<<<dim3((5120 + 255) / 256), b256, 0, stream>>>(fc1_w, Btfc1, 128, 40, 1);
  tcvt_kernel<<<dim3((262144 + 255) / 256), b256, 0, stream>>>(conv_w, Btconv, 256, 128, 8);
  tcvt_kernel<<<dim3((65536 + 255) / 256), b256, 0, stream>>>(genv_w, Btgenv, 128, 128, 4);

  // fc0: h = relu(x @ fc0_w + b); also emit hs = bf16(inv*h) for gather
  mgemm_kernel<<<dim3(MB), b256, 0, stream>>>(
      x, nullptr, DD, Btfc0, 256, 1, hA, HH, fc0_b, nullptr, 0, nullptr, nullptr,
      nullptr, hsb, inv, NN, HH);

  // conv layers
  float* hcur = hA;
  float* hnext = hB;
  for (int l = 0; l < 2; ++l) {
    env_softmax_kernel<<<dim3((NN + 63) / 64), b256, 0, stream>>>(
        hcur, env_w + (size_t)l * HH * KK, env_b + (size_t)l * KK, env, NN);
    gather_kernel<<<dim3(NN / 4), b256, 0, stream>>>(hsb, start, bucket, inv, agg, NN);
    // conv0 output also emits scaled bf16 copy for next layer's gather
    mconv_kernel<<<dim3(MB), b256, 0, stream>>>(
        agg, hcur, env, Btconv + (size_t)l * 131072, 256, 1, hcur, hnext,
        (l == 0) ? hsb : nullptr, inv, NN);
    float* t = hcur; hcur = hnext; hnext = t;
  }
  // hcur == hA

  // q, k, v (k/v also emit transposed bf16 copies)
  mgemm_kernel<<<dim3(MB), b256, 0, stream>>>(
      hcur, nullptr, HH, Btq, 128, 0, q, HH, q_b, nullptr, 0, nullptr, nullptr,
      nullptr, nullptr, nullptr, NN, HH);
  mgemm_kernel<<<dim3(MB), b256, 0, stream>>>(
      hcur, nullptr, HH, Btk, 128, 0, kb, HH, k_b, nullptr, 0, nullptr, nullptr,
      kTbf, nullptr, nullptr, NN, HH);
  mgemm_kernel<<<dim3(MB), b256, 0, stream>>>(
      hcur, nullptr, HH, Btv, 128, 0, vbuf, HH, v_b, nullptr, 0, nullptr, nullptr,
      vTbf, nullptr, nullptr, NN, HH);

  colstats1_kernel<<<dim3(CSB), b256, 0, stream>>>(q, kb, partK, partS, NN);
  colstats2_kernel<<<dim3(1), b256, 0, stream>>>(partK, partS, ksum, red);
  ktv_mfma_kernel<<<dim3(SKV), b256, 0, stream>>>(kTbf, vTbf, part);
  ktv_reduce_kernel<<<dim3(64), b256, 0, stream>>>(part, Btktv);
  scale_kernel<<<dim3(1), dim3(1), 0, stream>>>(red, NN);
  anorm_kernel<<<dim3((NN + 255) / 256), b256, 0, stream>>>(q, ksum, red, anorm, NN);

  // gr = (v + q @ ktv * red[2]) / anorm
  mgemm_kernel<<<dim3(MB), b256, 0, stream>>>(
      q, nullptr, HH, Btktv, 128, 3, gr, HH, nullptr, vbuf, HH, anorm, red,
      nullptr, nullptr, nullptr, NN, HH);

  // genv = softmax(gr @ envp_w + envp_b)
  env_softmax_kernel<<<dim3((NN + 63) / 64), b256, 0, stream>>>(gr, envp_w, envp_b, genv, NN);

  // ctx = sum_k genv[:,k] * (gr @ genv_w[k])
  mconv_kernel<<<dim3(MB), b256, 0, stream>>>(
      gr, nullptr, genv, Btgenv, 128, 0, nullptr, ctx, nullptr, nullptr, NN);

  // gh = relu(ctx @ gt_w + gt_b)
  mgemm_kernel<<<dim3(MB), b256, 0, stream>>>(
      ctx, nullptr, HH, Btgt, 128, 1, gh, HH, gt_b, nullptr, 0, nullptr, nullptr,
      nullptr, nullptr, nullptr, NN, HH);

  // out = 0.5*((h+gh) @ fc1_w) + fc1_b
  mgemm_kernel<<<dim3(MB), b256, 0, stream>>>(
      hcur, gh, HH, Btfc1, 128, 5, out, CC, fc1_b, nullptr, 0, nullptr, nullptr,
      nullptr, nullptr, nullptr, NN, CC);
}

// Round 9
// 904.245 us; speedup vs baseline: 2.0323x; 1.1594x over previous
//
#include <hip/hip_runtime.h>

#define DEV __device__ __forceinline__

static constexpr int NN = 50000;   // nodes
static constexpr int DD = 256;     // input dim
static constexpr int HH = 128;     // hidden
static constexpr int CC = 40;      // classes
static constexpr int KK = 4;       // envs
static constexpr int EE = 800000;  // edges
static constexpr int MP = 50176;   // padded node count (196*256, mult of 32)
static constexpr int SKV = 196;    // split-K blocks for ktv
static constexpr int CPB = 8;      // 32-node chunks per ktv block
static constexpr int CSB = 391;    // colstats / scan blocks (ceil(NN/128))

typedef __attribute__((ext_vector_type(8))) short bf16x8;
typedef __attribute__((ext_vector_type(4))) float f32x4;

DEV unsigned short f2bf(float f) {
  union { float f; unsigned int i; } c; c.f = f;
  unsigned int x = c.i;
  x += 0x7FFFu + ((x >> 16) & 1u);   // round-to-nearest-even
  return (unsigned short)(x >> 16);
}
DEV float bfbits2f(unsigned int hi16bits) {
  union { unsigned int i; float f; } c; c.i = hi16bits; return c.f;
}

// harness-named kernel (unused in pipeline)
__global__ void MLEI_12970801234193_kernel(float* out, int n) {
  int i = blockIdx.x * blockDim.x + threadIdx.x;
  if (i < n) out[i] = 7.0f;
}

__global__ void zero_i32_kernel(int* p, int n) {
  int i = blockIdx.x * blockDim.x + threadIdx.x;
  if (i < n) p[i] = 0;
}

// zero the pad columns [NN, MP) of the transposed bf16 k/v buffers
__global__ void padzero_kernel(unsigned short* kT, unsigned short* vT) {
  int i = blockIdx.x * blockDim.x + threadIdx.x;
  const int PW = MP - NN;  // 176
  if (i >= HH * PW) return;
  int f = i / PW, c = i - f * PW;
  kT[(size_t)f * MP + NN + c] = 0;
  vT[(size_t)f * MP + NN + c] = 0;
}

// transpose-convert: dst[m][n][k] = bf16(src[m][k][n]); nm matrices of K x N
__global__ void tcvt_kernel(const float* __restrict__ src, unsigned short* __restrict__ dst,
                            int K, int N, int nm) {
  int i = blockIdx.x * blockDim.x + threadIdx.x;
  int tot = nm * K * N;
  if (i >= tot) return;
  int m = i / (K * N);
  int rem = i - m * K * N;
  int k = rem / N;
  int n = rem - k * N;
  dst[(size_t)m * K * N + (size_t)n * K + k] = f2bf(src[i]);
}

// ---------------- generic bf16-MFMA GEMM ----------------
__global__ __launch_bounds__(256) void mgemm_kernel(
    const float* __restrict__ A, const float* __restrict__ Aadd, int lda,
    const unsigned short* __restrict__ Bt, int K,
    int emode, float* __restrict__ out, int ldo,
    const float* __restrict__ bias, const float* __restrict__ resid, int ldr,
    const float* __restrict__ anorm, const float* __restrict__ red,
    unsigned short* __restrict__ outT,
    unsigned short* __restrict__ outBf, const float* __restrict__ rowscale,
    int M, int Nd) {
  __shared__ unsigned short As[128][40];
  __shared__ unsigned short Bs[128][40];
  const int tid = threadIdx.x, lane = tid & 63, wave = tid >> 6;
  const int quad = lane >> 4, l16 = lane & 15;
  const int wm = (wave >> 1) * 64, wn = (wave & 1) * 64;
  const int bm = blockIdx.x * 128;
  const int srow = tid >> 1, skh = (tid & 1) * 16;

  f32x4 acc[4][4];
#pragma unroll
  for (int i = 0; i < 4; ++i)
#pragma unroll
    for (int j = 0; j < 4; ++j)
#pragma unroll
      for (int r = 0; r < 4; ++r) acc[i][j][r] = 0.f;

  for (int k0 = 0; k0 < K; k0 += 32) {
    {
      int grow = bm + srow;
      float va[16];
      if (grow < M) {
        const float* ap = A + (size_t)grow * lda + k0 + skh;
        float4 v0 = *(const float4*)(ap + 0), v1 = *(const float4*)(ap + 4);
        float4 v2 = *(const float4*)(ap + 8), v3 = *(const float4*)(ap + 12);
        va[0] = v0.x; va[1] = v0.y; va[2] = v0.z; va[3] = v0.w;
        va[4] = v1.x; va[5] = v1.y; va[6] = v1.z; va[7] = v1.w;
        va[8] = v2.x; va[9] = v2.y; va[10] = v2.z; va[11] = v2.w;
        va[12] = v3.x; va[13] = v3.y; va[14] = v3.z; va[15] = v3.w;
        if (Aadd) {
          const float* ap2 = Aadd + (size_t)grow * lda + k0 + skh;
          float4 w0 = *(const float4*)(ap2 + 0), w1 = *(const float4*)(ap2 + 4);
          float4 w2 = *(const float4*)(ap2 + 8), w3 = *(const float4*)(ap2 + 12);
          va[0] += w0.x; va[1] += w0.y; va[2] += w0.z; va[3] += w0.w;
          va[4] += w1.x; va[5] += w1.y; va[6] += w1.z; va[7] += w1.w;
          va[8] += w2.x; va[9] += w2.y; va[10] += w2.z; va[11] += w2.w;
          va[12] += w3.x; va[13] += w3.y; va[14] += w3.z; va[15] += w3.w;
        }
      } else {
#pragma unroll
        for (int z = 0; z < 16; ++z) va[z] = 0.f;
      }
      bf16x8 p0, p1;
#pragma unroll
      for (int z = 0; z < 8; ++z) { p0[z] = (short)f2bf(va[z]); p1[z] = (short)f2bf(va[z + 8]); }
      *(bf16x8*)&As[srow][skh] = p0;
      *(bf16x8*)&As[srow][skh + 8] = p1;
      bf16x8 b0, b1;
      if (srow < Nd) {
        const unsigned short* bp = Bt + (size_t)srow * K + k0 + skh;
        b0 = *(const bf16x8*)(bp);
        b1 = *(const bf16x8*)(bp + 8);
      } else {
#pragma unroll
        for (int z = 0; z < 8; ++z) { b0[z] = 0; b1[z] = 0; }
      }
      *(bf16x8*)&Bs[srow][skh] = b0;
      *(bf16x8*)&Bs[srow][skh + 8] = b1;
    }
    __syncthreads();
    bf16x8 af[4], bfr[4];
#pragma unroll
    for (int i = 0; i < 4; ++i) af[i] = *(const bf16x8*)&As[wm + i * 16 + l16][quad * 8];
#pragma unroll
    for (int j = 0; j < 4; ++j) bfr[j] = *(const bf16x8*)&Bs[wn + j * 16 + l16][quad * 8];
#pragma unroll
    for (int i = 0; i < 4; ++i)
#pragma unroll
      for (int j = 0; j < 4; ++j)
        acc[i][j] = __builtin_amdgcn_mfma_f32_16x16x32_bf16(af[i], bfr[j], acc[i][j], 0, 0, 0);
    __syncthreads();
  }

  float s2 = (emode == 3) ? red[2] : 0.f;
#pragma unroll
  for (int j = 0; j < 4; ++j) {
    int col = wn + j * 16 + l16;
    if (col >= Nd) continue;
    float bv = bias ? bias[col] : 0.f;
#pragma unroll
    for (int i = 0; i < 4; ++i) {
      int row0 = bm + wm + i * 16 + quad * 4;
      if (row0 >= M) continue;
      float o[4];
#pragma unroll
      for (int r = 0; r < 4; ++r) {
        float a = acc[i][j][r];
        int row = row0 + r;
        if (emode == 0) o[r] = a + bv;
        else if (emode == 1) o[r] = fmaxf(a + bv, 0.f);
        else if (emode == 3) o[r] = (resid[(size_t)row * ldr + col] + a * s2) / anorm[row];
        else o[r] = 0.5f * a + bv;
        out[(size_t)row * ldo + col] = o[r];
      }
      if (outT) {
        ushort4 pk;
        pk.x = f2bf(o[0]); pk.y = f2bf(o[1]); pk.z = f2bf(o[2]); pk.w = f2bf(o[3]);
        *(ushort4*)&outT[(size_t)col * MP + row0] = pk;
      }
      if (outBf) {
#pragma unroll
        for (int r = 0; r < 4; ++r) {
          float rs = rowscale ? rowscale[row0 + r] : 1.f;
          outBf[(size_t)(row0 + r) * 128 + col] = f2bf(o[r] * rs);
        }
      }
    }
  }
}

// ---------------- split-K MFMA kT@v ----------------
__global__ __launch_bounds__(256) void ktv_mfma_kernel(
    const unsigned short* __restrict__ kT, const unsigned short* __restrict__ vT,
    float* __restrict__ part) {
  __shared__ unsigned short As[128][40];
  __shared__ unsigned short Bs[128][40];
  const int tid = threadIdx.x, lane = tid & 63, wave = tid >> 6;
  const int quad = lane >> 4, l16 = lane & 15;
  const int wm = (wave >> 1) * 64, wn = (wave & 1) * 64;
  const int srow = tid >> 1, skh = (tid & 1) * 16;

  f32x4 acc[4][4];
#pragma unroll
  for (int i = 0; i < 4; ++i)
#pragma unroll
    for (int j = 0; j < 4; ++j)
#pragma unroll
      for (int r = 0; r < 4; ++r) acc[i][j][r] = 0.f;

  const int nb0 = blockIdx.x * (CPB * 32);
  for (int c = 0; c < CPB; ++c) {
    int nb = nb0 + c * 32;
    const unsigned short* kp = kT + (size_t)srow * MP + nb + skh;
    *(bf16x8*)&As[srow][skh] = *(const bf16x8*)(kp);
    *(bf16x8*)&As[srow][skh + 8] = *(const bf16x8*)(kp + 8);
    const unsigned short* vp = vT + (size_t)srow * MP + nb + skh;
    *(bf16x8*)&Bs[srow][skh] = *(const bf16x8*)(vp);
    *(bf16x8*)&Bs[srow][skh + 8] = *(const bf16x8*)(vp + 8);
    __syncthreads();
    bf16x8 af[4], bfr[4];
#pragma unroll
    for (int i = 0; i < 4; ++i) af[i] = *(const bf16x8*)&As[wm + i * 16 + l16][quad * 8];
#pragma unroll
    for (int j = 0; j < 4; ++j) bfr[j] = *(const bf16x8*)&Bs[wn + j * 16 + l16][quad * 8];
#pragma unroll
    for (int i = 0; i < 4; ++i)
#pragma unroll
      for (int j = 0; j < 4; ++j)
        acc[i][j] = __builtin_amdgcn_mfma_f32_16x16x32_bf16(af[i], bfr[j], acc[i][j], 0, 0, 0);
    __syncthreads();
  }

  float* pb = part + (size_t)blockIdx.x * 16384;
#pragma unroll
  for (int j = 0; j < 4; ++j) {
    int col = wn + j * 16 + l16;
#pragma unroll
    for (int i = 0; i < 4; ++i) {
      int row0 = wm + i * 16 + quad * 4;
      *(f32x4*)&pb[col * 128 + row0] = acc[i][j];
    }
  }
}

__global__ void ktv_reduce_kernel(const float* __restrict__ part,
                                  unsigned short* __restrict__ Btktv) {
  int i = blockIdx.x * blockDim.x + threadIdx.x;
  if (i >= 16384) return;
  float s = 0.f;
  for (int b = 0; b < SKV; ++b) s += part[(size_t)b * 16384 + i];
  Btktv[i] = f2bf(s);
}

// ---------------- env-weighted MFMA GEMM (conv & ctx) ----------------
__global__ __launch_bounds__(256) void mconv_kernel(
    const float* __restrict__ A1, const float* __restrict__ A2,
    const float* __restrict__ env, const unsigned short* __restrict__ Btc, int Kpe,
    int relu_resid, const float* __restrict__ resid, float* __restrict__ out,
    unsigned short* __restrict__ outBf, const float* __restrict__ rowscale, int M) {
  __shared__ unsigned short As[128][40];
  __shared__ unsigned short Bs[128][40];
  __shared__ float envs[128][4];
  const int tid = threadIdx.x, lane = tid & 63, wave = tid >> 6;
  const int quad = lane >> 4, l16 = lane & 15;
  const int wm = (wave >> 1) * 64, wn = (wave & 1) * 64;
  const int bm = blockIdx.x * 128;
  const int srow = tid >> 1, skh = (tid & 1) * 16;

  for (int i = tid; i < 512; i += 256) {
    int r = i >> 2, c = i & 3;
    int g = bm + r;
    envs[r][c] = (g < M) ? env[(size_t)g * 4 + c] : 0.f;
  }

  f32x4 acc[4][4];
#pragma unroll
  for (int i = 0; i < 4; ++i)
#pragma unroll
    for (int j = 0; j < 4; ++j)
#pragma unroll
      for (int r = 0; r < 4; ++r) acc[i][j][r] = 0.f;

  const int nch = Kpe >> 5;
  for (int e = 0; e < 4; ++e) {
    f32x4 p[4][4];
#pragma unroll
    for (int i = 0; i < 4; ++i)
#pragma unroll
      for (int j = 0; j < 4; ++j)
#pragma unroll
        for (int r = 0; r < 4; ++r) p[i][j][r] = 0.f;

    for (int kc = 0; kc < nch; ++kc) {
      int kof = kc * 32;
      const float* Asrc = A1;
      int ks = kof;
      if (A2 && kof >= 128) { Asrc = A2; ks = kof - 128; }
      {
        int grow = bm + srow;
        float va[16];
        if (grow < M) {
          const float* ap = Asrc + (size_t)grow * 128 + ks + skh;
          float4 v0 = *(const float4*)(ap + 0), v1 = *(const float4*)(ap + 4);
          float4 v2 = *(const float4*)(ap + 8), v3 = *(const float4*)(ap + 12);
          va[0] = v0.x; va[1] = v0.y; va[2] = v0.z; va[3] = v0.w;
          va[4] = v1.x; va[5] = v1.y; va[6] = v1.z; va[7] = v1.w;
          va[8] = v2.x; va[9] = v2.y; va[10] = v2.z; va[11] = v2.w;
          va[12] = v3.x; va[13] = v3.y; va[14] = v3.z; va[15] = v3.w;
        } else {
#pragma unroll
          for (int z = 0; z < 16; ++z) va[z] = 0.f;
        }
        bf16x8 p0, p1;
#pragma unroll
        for (int z = 0; z < 8; ++z) { p0[z] = (short)f2bf(va[z]); p1[z] = (short)f2bf(va[z + 8]); }
        *(bf16x8*)&As[srow][skh] = p0;
        *(bf16x8*)&As[srow][skh + 8] = p1;
        const unsigned short* bp = Btc + ((size_t)e * 128 + srow) * Kpe + kof + skh;
        bf16x8 b0 = *(const bf16x8*)(bp);
        bf16x8 b1 = *(const bf16x8*)(bp + 8);
        *(bf16x8*)&Bs[srow][skh] = b0;
        *(bf16x8*)&Bs[srow][skh + 8] = b1;
      }
      __syncthreads();
      bf16x8 af[4], bfr[4];
#pragma unroll
      for (int i = 0; i < 4; ++i) af[i] = *(const bf16x8*)&As[wm + i * 16 + l16][quad * 8];
#pragma unroll
      for (int j = 0; j < 4; ++j) bfr[j] = *(const bf16x8*)&Bs[wn + j * 16 + l16][quad * 8];
#pragma unroll
      for (int i = 0; i < 4; ++i)
#pragma unroll
        for (int j = 0; j < 4; ++j)
          p[i][j] = __builtin_amdgcn_mfma_f32_16x16x32_bf16(af[i], bfr[j], p[i][j], 0, 0, 0);
      __syncthreads();
    }
#pragma unroll
    for (int i = 0; i < 4; ++i) {
      float ev[4];
#pragma unroll
      for (int r = 0; r < 4; ++r) ev[r] = envs[wm + i * 16 + quad * 4 + r][e];
#pragma unroll
      for (int j = 0; j < 4; ++j)
#pragma unroll
        for (int r = 0; r < 4; ++r) acc[i][j][r] += ev[r] * p[i][j][r];
    }
  }

#pragma unroll
  for (int j = 0; j < 4; ++j) {
    int col = wn + j * 16 + l16;
#pragma unroll
    for (int i = 0; i < 4; ++i) {
      int row0 = bm + wm + i * 16 + quad * 4;
      if (row0 >= M) continue;
#pragma unroll
      for (int r = 0; r < 4; ++r) {
        int row = row0 + r;
        float a = acc[i][j][r];
        float o = relu_resid ? fmaxf(a + resid[(size_t)row * 128 + col], 0.f) : a;
        out[(size_t)row * 128 + col] = o;
        if (outBf) {
          float rs = rowscale ? rowscale[row] : 1.f;
          outBf[(size_t)row * 128 + col] = f2bf(o * rs);
        }
      }
    }
  }
}

// ---------------- graph kernels ----------------
__global__ void count_kernel(const int* ei, int* deg, int E) {
  int e = blockIdx.x * blockDim.x + threadIdx.x;
  if (e >= E) return;
  atomicAdd(&deg[ei[E + e]], 1);
}

// 3-phase parallel prefix scan over deg[0..n)
// phase 1: per-block (128-wide) sums
__global__ __launch_bounds__(128) void scan1_kernel(const int* __restrict__ deg,
                                                    int* __restrict__ bsum, int n) {
  __shared__ int sh[128];
  int t = threadIdx.x;
  int i = blockIdx.x * 128 + t;
  sh[t] = (i < n) ? deg[i] : 0;
  __syncthreads();
  for (int off = 64; off > 0; off >>= 1) {
    if (t < off) sh[t] += sh[t + off];
    __syncthreads();
  }
  if (t == 0) bsum[blockIdx.x] = sh[0];
}

// phase 2: exclusive scan of block sums (nb <= 512), writes start[n] = total
__global__ __launch_bounds__(512) void scan2_kernel(const int* __restrict__ bsum,
                                                    int* __restrict__ boff, int nb,
                                                    int* __restrict__ startN) {
  __shared__ int sh[512];
  int t = threadIdx.x;
  int v0 = (t < nb) ? bsum[t] : 0;
  sh[t] = v0;
  __syncthreads();
  for (int off = 1; off < 512; off <<= 1) {
    int v = sh[t];
    int add = (t >= off) ? sh[t - off] : 0;
    __syncthreads();
    sh[t] = v + add;
    __syncthreads();
  }
  if (t < nb) boff[t] = sh[t] - v0;
  if (t == nb - 1) *startN = sh[t];
}

// phase 3: in-block exclusive scan + write start/cursor/inv
__global__ __launch_bounds__(128) void scan3_kernel(const int* __restrict__ deg,
                                                    const int* __restrict__ boff,
                                                    int* __restrict__ start,
                                                    int* __restrict__ cursor,
                                                    float* __restrict__ inv, int n) {
  __shared__ int sh[128];
  int t = threadIdx.x;
  int i = blockIdx.x * 128 + t;
  int d = (i < n) ? deg[i] : 0;
  sh[t] = d;
  __syncthreads();
  for (int off = 1; off < 128; off <<= 1) {
    int v = sh[t];
    int add = (t >= off) ? sh[t - off] : 0;
    __syncthreads();
    sh[t] = v + add;
    __syncthreads();
  }
  if (i < n) {
    int p = boff[blockIdx.x] + sh[t] - d;
    start[i] = p; cursor[i] = p;
    inv[i] = (d > 0) ? rsqrtf((float)d) : 0.f;
  }
}

__global__ void fill_kernel(const int* ei, int* cursor, int* bucket, int E) {
  int e = blockIdx.x * blockDim.x + threadIdx.x;
  if (e >= E) return;
  int r = ei[e], c = ei[E + e];
  int pos = atomicAdd(&cursor[c], 1);
  bucket[pos] = r;
}

// gather from pre-scaled bf16 h: agg[n,f] = inv[n] * sum_edges hs[src][f]
__global__ __launch_bounds__(256) void gather_kernel(
    const unsigned short* __restrict__ hs, const int* __restrict__ start,
    const int* __restrict__ bucket, const float* __restrict__ inv,
    float* __restrict__ agg, int n) {
  int node = blockIdx.x * 4 + (threadIdx.x >> 6);
  if (node >= n) return;
  int f2 = (threadIdx.x & 63) * 2;
  int s0 = start[node], s1 = start[node + 1];
  float a0 = 0.f, a1 = 0.f;
  for (int j = s0; j < s1; ++j) {
    int r = bucket[j];
    unsigned int u = *(const unsigned int*)&hs[(size_t)r * 128 + f2];
    a0 += bfbits2f(u << 16);
    a1 += bfbits2f(u & 0xFFFF0000u);
  }
  float iv = inv[node];
  *(float2*)&agg[(size_t)node * 128 + f2] = make_float2(iv * a0, iv * a1);
}

// ---------------- env softmax ----------------
__global__ __launch_bounds__(256) void env_softmax_kernel(const float* __restrict__ h,
                                                          const float* __restrict__ w,
                                                          const float* __restrict__ b,
                                                          float* __restrict__ env, int M) {
  __shared__ float hsd[64][129];
  __shared__ float ws[HH * KK];
  int tid = threadIdx.x;
  int base = blockIdx.x * 64;
  for (int i = tid; i < HH * KK; i += 256) ws[i] = w[i];
  {
    int row = tid >> 2, q4 = (tid & 3) * 32;
    int g = base + row;
    if (g < M) {
      const float* hp = h + (size_t)g * HH + q4;
#pragma unroll
      for (int z = 0; z < 8; ++z) {
        float4 v = *(const float4*)(hp + z * 4);
        hsd[row][q4 + z * 4 + 0] = v.x; hsd[row][q4 + z * 4 + 1] = v.y;
        hsd[row][q4 + z * 4 + 2] = v.z; hsd[row][q4 + z * 4 + 3] = v.w;
      }
    }
  }
  __syncthreads();
  if (tid < 64 && base + tid < M) {
    float l0 = b[0], l1 = b[1], l2 = b[2], l3 = b[3];
    for (int d = 0; d < HH; ++d) {
      float hv = hsd[tid][d];
      l0 += hv * ws[d * 4 + 0]; l1 += hv * ws[d * 4 + 1];
      l2 += hv * ws[d * 4 + 2]; l3 += hv * ws[d * 4 + 3];
    }
    float m = fmaxf(fmaxf(l0, l1), fmaxf(l2, l3));
    float e0 = __expf(l0 - m), e1 = __expf(l1 - m), e2 = __expf(l2 - m), e3 = __expf(l3 - m);
    float s = 1.f / (e0 + e1 + e2 + e3);
    *(float4*)(env + (size_t)(base + tid) * KK) = make_float4(e0 * s, e1 * s, e2 * s, e3 * s);
  }
}

// ---------------- two-stage colstats ----------------
__global__ __launch_bounds__(256) void colstats1_kernel(
    const float* __restrict__ q, const float* __restrict__ k,
    float* __restrict__ partK, float* __restrict__ partS, int n) {
  int tid = threadIdx.x, ty = tid >> 7, tx = tid & 127;
  int lo = blockIdx.x * 128 + ty, hi = min(n, blockIdx.x * 128 + 128);
  float ks = 0.f, sq = 0.f, sk = 0.f;
  for (int r = lo; r < hi; r += 2) {
    float kv = k[(size_t)r * HH + tx];
    float qv = q[(size_t)r * HH + tx];
    ks += kv; sq += qv * qv; sk += kv * kv;
  }
  __shared__ float sks[2][128];
  __shared__ float ssq[256], ssk[256];
  sks[ty][tx] = ks; ssq[tid] = sq; ssk[tid] = sk;
  __syncthreads();
  if (ty == 0) partK[(size_t)blockIdx.x * 128 + tx] = sks[0][tx] + sks[1][tx];
  for (int off = 128; off > 0; off >>= 1) {
    if (tid < off) { ssq[tid] += ssq[tid + off]; ssk[tid] += ssk[tid + off]; }
    __syncthreads();
  }
  if (tid == 0) { partS[blockIdx.x * 2] = ssq[0]; partS[blockIdx.x * 2 + 1] = ssk[0]; }
}

__global__ __launch_bounds__(256) void colstats2_kernel(
    const float* __restrict__ partK, const float* __restrict__ partS,
    float* __restrict__ ksum, float* __restrict__ red) {
  int t = threadIdx.x;
  if (t < 128) {
    float s = 0.f;
    for (int b = 0; b < CSB; ++b) s += partK[(size_t)b * 128 + t];
    ksum[t] = s;
  } else if (t == 128 || t == 129) {
    float s = 0.f;
    for (int b = 0; b < CSB; ++b) s += partS[b * 2 + (t - 128)];
    red[t - 128] = s;
  }
}

__global__ void scale_kernel(float* red, int n) {
  float nq = fmaxf(sqrtf(red[0]), 1e-12f);
  float nk = fmaxf(sqrtf(red[1]), 1e-12f);
  red[2] = 1.f / (nq * nk * (float)n);
}

__global__ __launch_bounds__(256) void anorm_kernel(const float* q, const float* ksum,
                                                    const float* red, float* anorm, int M) {
  __shared__ float ks[HH];
  for (int i = threadIdx.x; i < HH; i += blockDim.x) ks[i] = ksum[i];
  __syncthreads();
  int n = blockIdx.x * blockDim.x + threadIdx.x;
  if (n >= M) return;
  const float* qp = q + (size_t)n * HH;
  float d = 0.f;
  for (int i = 0; i < HH; ++i) d += qp[i] * ks[i];
  float a = 1.f + d * red[2];
  anorm[n] = fmaxf(a, 1e-12f);
}

// ---------------- host launcher ----------------
extern "C" void kernel_launch(void* const* d_in, const int* in_sizes, int n_in,
                              void* d_out, int out_size, void* d_ws, size_t ws_size,
                              hipStream_t stream) {
  const float* x = (const float*)d_in[0];
  const int* ei = (const int*)d_in[1];
  const float* fc0_w = (const float*)d_in[2];
  const float* fc0_b = (const float*)d_in[3];
  const float* fc1_w = (const float*)d_in[4];
  const float* fc1_b = (const float*)d_in[5];
  const float* env_w = (const float*)d_in[6];
  const float* env_b = (const float*)d_in[7];
  const float* conv_w = (const float*)d_in[8];
  const float* q_w = (const float*)d_in[9];
  const float* q_b = (const float*)d_in[10];
  const float* k_w = (const float*)d_in[11];
  const float* k_b = (const float*)d_in[12];
  const float* v_w = (const float*)d_in[13];
  const float* v_b = (const float*)d_in[14];
  const float* envp_w = (const float*)d_in[15];
  const float* envp_b = (const float*)d_in[16];
  const float* genv_w = (const float*)d_in[17];
  const float* gt_w = (const float*)d_in[18];
  const float* gt_b = (const float*)d_in[19];
  float* out = (float*)d_out;

  const size_t NH = (size_t)NN * HH;
  float* W = (float*)d_ws;
  float* hA = W;             // final h
  float* hB = W + NH;        // layer buffer -> k -> ctx
  float* agg = W + 2 * NH;   // agg -> q
  float* vbuf = W + 3 * NH;  // v -> gh
  float* gr = W + 4 * NH;
  float* env = W + 5 * NH;
  float* genv = env + (size_t)NN * KK;
  float* inv = genv + (size_t)NN * KK;
  float* anorm = inv + NN;
  float* ksum = anorm + NN;
  float* red = ksum + HH;
  int* deg = (int*)(red + 4);
  int* start = deg + NN;
  int* cursor = start + NN + 1;
  int* bucket = cursor + NN;
  int* bsum = bucket + EE;          // CSB
  int* boff = bsum + CSB;           // CSB
  unsigned short* wb = (unsigned short*)(((uintptr_t)(boff + CSB) + 15) & ~(uintptr_t)15);
  unsigned short* Btfc0 = wb;                 // 256*128
  unsigned short* Btq = Btfc0 + 32768;
  unsigned short* Btk = Btq + 16384;
  unsigned short* Btv = Btk + 16384;
  unsigned short* Btgt = Btv + 16384;
  unsigned short* Btfc1 = Btgt + 16384;       // 40*128
  unsigned short* Btconv = Btfc1 + 5120;      // 2*4*128*256
  unsigned short* Btgenv = Btconv + 262144;   // 4*128*128
  unsigned short* Btktv = Btgenv + 65536;     // 128*128
  unsigned short* kTbf = Btktv + 16384;       // 128*MP
  unsigned short* vTbf = kTbf + (size_t)HH * MP;
  unsigned short* hsb = vTbf + (size_t)HH * MP;  // NN*128 bf16 (scaled h)
  float* part = (float*)(((uintptr_t)(hsb + NH) + 15) & ~(uintptr_t)15);  // SKV*16384
  float* partK = part + (size_t)SKV * 16384;  // CSB*128
  float* partS = partK + (size_t)CSB * 128;   // CSB*2

  float* q = agg;
  float* kb = hB;
  float* ctx = hB;
  float* gh = vbuf;

  dim3 b256(256);
  const int MB = (NN + 127) / 128;  // 391

  zero_i32_kernel<<<dim3((NN + 255) / 256), b256, 0, stream>>>(deg, NN);
  padzero_kernel<<<dim3((HH * (MP - NN) + 255) / 256), b256, 0, stream>>>(kTbf, vTbf);

  // CSR build (parallel 3-phase scan)
  count_kernel<<<dim3((EE + 255) / 256), b256, 0, stream>>>(ei, deg, EE);
  scan1_kernel<<<dim3(CSB), dim3(128), 0, stream>>>(deg, bsum, NN);
  scan2_kernel<<<dim3(1), dim3(512), 0, stream>>>(bsum, boff, CSB, start + NN);
  scan3_kernel<<<dim3(CSB), dim3(128), 0, stream>>>(deg, boff, start, cursor, inv, NN);
  fill_kernel<<<dim3((EE + 255) / 256), b256, 0, stream>>>(ei, cursor, bucket, EE);

  // weight prep
  tcvt_kernel<<<dim3((32768 + 255) / 256), b256, 0, stream>>>(fc0_w, Btfc0, 256, 128, 1);
  tcvt_kernel<<<dim3((16384 + 255) / 256), b256, 0, stream>>>(q_w, Btq, 128, 128, 1);
  tcvt_kernel<<<dim3((16384 + 255) / 256), b256, 0, stream>>>(k_w, Btk, 128, 128, 1);
  tcvt_kernel<<<dim3((16384 + 255) / 256), b256, 0, stream>>>(v_w, Btv, 128, 128, 1);
  tcvt_kernel<<<dim3((16384 + 255) / 256), b256, 0, stream>>>(gt_w, Btgt, 128, 128, 1);
  tcvt_kernel<<<dim3((5120 + 255) / 256), b256, 0, stream>>>(fc1_w, Btfc1, 128, 40, 1);
  tcvt_kernel<<<dim3((262144 + 255) / 256), b256, 0, stream>>>(conv_w, Btconv, 256, 128, 8);
  tcvt_kernel<<<dim3((65536 + 255) / 256), b256, 0, stream>>>(genv_w, Btgenv, 128, 128, 4);

  // fc0: h = relu(x @ fc0_w + b); also emit hs = bf16(inv*h) for gather
  mgemm_kernel<<<dim3(MB), b256, 0, stream>>>(
      x, nullptr, DD, Btfc0, 256, 1, hA, HH, fc0_b, nullptr, 0, nullptr, nullptr,
      nullptr, hsb, inv, NN, HH);

  // conv layers
  float* hcur = hA;
  float* hnext = hB;
  for (int l = 0; l < 2; ++l) {
    env_softmax_kernel<<<dim3((NN + 63) / 64), b256, 0, stream>>>(
        hcur, env_w + (size_t)l * HH * KK, env_b + (size_t)l * KK, env, NN);
    gather_kernel<<<dim3(NN / 4), b256, 0, stream>>>(hsb, start, bucket, inv, agg, NN);
    mconv_kernel<<<dim3(MB), b256, 0, stream>>>(
        agg, hcur, env, Btconv + (size_t)l * 131072, 256, 1, hcur, hnext,
        (l == 0) ? hsb : nullptr, inv, NN);
    float* t = hcur; hcur = hnext; hnext = t;
  }
  // hcur == hA

  // q, k, v (k/v also emit transposed bf16 copies)
  mgemm_kernel<<<dim3(MB), b256, 0, stream>>>(
      hcur, nullptr, HH, Btq, 128, 0, q, HH, q_b, nullptr, 0, nullptr, nullptr,
      nullptr, nullptr, nullptr, NN, HH);
  mgemm_kernel<<<dim3(MB), b256, 0, stream>>>(
      hcur, nullptr, HH, Btk, 128, 0, kb, HH, k_b, nullptr, 0, nullptr, nullptr,
      kTbf, nullptr, nullptr, NN, HH);
  mgemm_kernel<<<dim3(MB), b256, 0, stream>>>(
      hcur, nullptr, HH, Btv, 128, 0, vbuf, HH, v_b, nullptr, 0, nullptr, nullptr,
      vTbf, nullptr, nullptr, NN, HH);

  colstats1_kernel<<<dim3(CSB), b256, 0, stream>>>(q, kb, partK, partS, NN);
  colstats2_kernel<<<dim3(1), b256, 0, stream>>>(partK, partS, ksum, red);
  ktv_mfma_kernel<<<dim3(SKV), b256, 0, stream>>>(kTbf, vTbf, part);
  ktv_reduce_kernel<<<dim3(64), b256, 0, stream>>>(part, Btktv);
  scale_kernel<<<dim3(1), dim3(1), 0, stream>>>(red, NN);
  anorm_kernel<<<dim3((NN + 255) / 256), b256, 0, stream>>>(q, ksum, red, anorm, NN);

  // gr = (v + q @ ktv * red[2]) / anorm
  mgemm_kernel<<<dim3(MB), b256, 0, stream>>>(
      q, nullptr, HH, Btktv, 128, 3, gr, HH, nullptr, vbuf, HH, anorm, red,
      nullptr, nullptr, nullptr, NN, HH);

  // genv = softmax(gr @ envp_w + envp_b)
  env_softmax_kernel<<<dim3((NN + 63) / 64), b256, 0, stream>>>(gr, envp_w, envp_b, genv, NN);

  // ctx = sum_k genv[:,k] * (gr @ genv_w[k])
  mconv_kernel<<<dim3(MB), b256, 0, stream>>>(
      gr, nullptr, genv, Btgenv, 128, 0, nullptr, ctx, nullptr, nullptr, NN);

  // gh = relu(ctx @ gt_w + gt_b)
  mgemm_kernel<<<dim3(MB), b256, 0, stream>>>(
      ctx, nullptr, HH, Btgt, 128, 1, gh, HH, gt_b, nullptr, 0, nullptr, nullptr,
      nullptr, nullptr, nullptr, NN, HH);

  // out = 0.5*((h+gh) @ fc1_w) + fc1_b
  mgemm_kernel<<<dim3(MB), b256, 0, stream>>>(
      hcur, gh, HH, Btfc1, 128, 5, out, CC, fc1_b, nullptr, 0, nullptr, nullptr,
      nullptr, nullptr, nullptr, NN, CC);
}